// Round 1
// baseline (1708.685 us; speedup 1.0000x reference)
//
#include <hip/hip_runtime.h>

#define LEAKY_SLOPE 0.2f

// ---------------- utility kernels ----------------

__global__ __launch_bounds__(256) void k_zero(int* __restrict__ p, int n) {
  int i = blockIdx.x * 256 + threadIdx.x;
  if (i < n) p[i] = 0;
}

__global__ __launch_bounds__(64) void k_softmax3(const float* __restrict__ a_att,
                                                 const float* __restrict__ r_att,
                                                 float* __restrict__ a_soft) {
  if (threadIdx.x == 0) {
    float m = fmaxf(fmaxf(a_att[0], a_att[1]), a_att[2]);
    float e0 = expf(a_att[0] - m), e1 = expf(a_att[1] - m), e2 = expf(a_att[2] - m);
    float s = 1.0f / (e0 + e1 + e2);
    a_soft[0] = e0 * s; a_soft[1] = e1 * s; a_soft[2] = e2 * s;
    m = fmaxf(fmaxf(r_att[0], r_att[1]), r_att[2]);
    e0 = expf(r_att[0] - m); e1 = expf(r_att[1] - m); e2 = expf(r_att[2] - m);
    s = 1.0f / (e0 + e1 + e2);
    a_soft[3] = e0 * s; a_soft[4] = e1 * s; a_soft[5] = e2 * s;
  }
}

__global__ __launch_bounds__(256) void k_bitmap(const int* __restrict__ lidx,
                                                unsigned* __restrict__ bm, int L) {
  int i = blockIdx.x * 256 + threadIdx.x;
  if (i < L) {
    int n = lidx[i];
    atomicOr(&bm[n >> 5], 1u << (n & 31));
  }
}

// Count layer-1 in-degrees for all edges; for edges whose layer-2 destination
// (col) is a labeled node, also count deg2 and append to the hit list.
__global__ __launch_bounds__(256) void k_edge_scan(const int* __restrict__ rows,
                                                   const int* __restrict__ cols,
                                                   int* __restrict__ deg1, int* __restrict__ deg2,
                                                   const unsigned* __restrict__ bm,
                                                   int* __restrict__ hsrc, int* __restrict__ hpack,
                                                   int* __restrict__ counter, int N, int E) {
  int e = blockIdx.x * 256 + threadIdx.x;
  int rel = blockIdx.y;
  if (e >= E) return;
  int r = rows[rel * E + e];   // layer-1 dest / layer-2 src
  int c = cols[rel * E + e];   // layer-1 src / layer-2 dest
  atomicAdd(&deg1[rel * N + r], 1);
  if ((bm[c >> 5] >> (c & 31)) & 1u) {
    atomicAdd(&deg2[rel * N + c], 1);
    int pos = atomicAdd(counter, 1);
    hsrc[pos] = r;
    hpack[pos] = (rel << 20) | c;   // N=50000 < 2^20
  }
}

// ---------------- prefix sum (3 kernels) ----------------

__global__ __launch_bounds__(256) void k_scan1(const int* __restrict__ deg1,
                                               int* __restrict__ row_ptr,
                                               int* __restrict__ chunk_sums, int N) {
  __shared__ int sd[256];
  int tid = threadIdx.x;
  int n0 = blockIdx.x * 1024 + tid * 4;
  int v[4];
#pragma unroll
  for (int i = 0; i < 4; ++i) {
    int n = n0 + i;
    v[i] = (n < N) ? (deg1[n] + deg1[N + n] + deg1[2 * N + n]) : 0;
  }
  sd[tid] = v[0] + v[1] + v[2] + v[3];
  __syncthreads();
  for (int off = 1; off < 256; off <<= 1) {
    int t = (tid >= off) ? sd[tid - off] : 0;
    __syncthreads();
    sd[tid] += t;
    __syncthreads();
  }
  int run = tid ? sd[tid - 1] : 0;
#pragma unroll
  for (int i = 0; i < 4; ++i) {
    int n = n0 + i;
    if (n < N) row_ptr[n] = run;
    run += v[i];
  }
  if (tid == 255) chunk_sums[blockIdx.x] = sd[255];
}

__global__ __launch_bounds__(64) void k_scan2(const int* __restrict__ chunk_sums,
                                              int* __restrict__ chunk_offs,
                                              int nchunks, int* __restrict__ row_ptr, int N) {
  int lane = threadIdx.x;
  int mine = (lane < nchunks) ? chunk_sums[lane] : 0;
  int v = mine;
  for (int off = 1; off < 64; off <<= 1) {
    int t = __shfl_up(v, off, 64);
    if (lane >= off) v += t;
  }
  if (lane < nchunks) chunk_offs[lane] = v - mine;
  int total = __shfl(v, nchunks - 1, 64);
  if (lane == 0) row_ptr[N] = total;
}

__global__ __launch_bounds__(256) void k_scan3(int* __restrict__ row_ptr,
                                               const int* __restrict__ chunk_offs,
                                               int* __restrict__ fill_pos, int N) {
  int n = blockIdx.x * 256 + threadIdx.x;
  if (n < N) {
    int val = row_ptr[n] + chunk_offs[n >> 10];
    row_ptr[n] = val;
    fill_pos[n] = val;
  }
}

// ---------------- CSR scatter (combined over relations, keyed by dest) ----------------

__global__ __launch_bounds__(256) void k_scatter(const int* __restrict__ rows,
                                                 const int* __restrict__ cols,
                                                 const float* __restrict__ a_soft,
                                                 const int* __restrict__ deg1,
                                                 int* __restrict__ fill_pos,
                                                 int* __restrict__ esrc, float* __restrict__ ew,
                                                 int N, int E) {
  int e = blockIdx.x * 256 + threadIdx.x;
  int rel = blockIdx.y;
  if (e >= E) return;
  int d = rows[rel * E + e], s = cols[rel * E + e];
  int pos = atomicAdd(&fill_pos[d], 1);
  esrc[pos] = s;
  ew[pos] = a_soft[rel] / (float)deg1[rel * N + d];   // deg>=1 since edge exists
}

// ---------------- dense GEMM: out[M][128] = A[M][K] @ W[K][128] + bias ----------------
// 256 threads = 4 waves; wave handles 8 rows, lane handles 2 cols -> 32x128 per block.

__global__ __launch_bounds__(256) void k_gemm_bias(const float* __restrict__ A,
                                                   const float* __restrict__ W,
                                                   const float* __restrict__ bias,
                                                   float* __restrict__ out, int M, int K) {
  __shared__ float sW[64][128];   // 32 KB
  __shared__ float sA[32][64];    // 8 KB
  int tid = threadIdx.x;
  int wave = tid >> 6, lane = tid & 63;
  int lane2 = lane * 2;
  int row0 = blockIdx.x * 32;
  float acc[8][2] = {};
  for (int k0 = 0; k0 < K; k0 += 64) {       // K=300 -> 64,64,64,64,44 (all even, %4==0)
    int kc = min(64, K - k0);
    __syncthreads();
    for (int i = tid; i < kc * 32; i += 256) {
      int kk = i >> 5, c4 = i & 31;
      ((float4*)&sW[kk][0])[c4] = ((const float4*)&W[(size_t)(k0 + kk) * 128])[c4];
    }
    int kq4 = kc >> 2;
    for (int i = tid; i < 32 * kq4; i += 256) {
      int r = i / kq4, kq = i - r * kq4;
      int gr = row0 + r;
      float4 v = make_float4(0.f, 0.f, 0.f, 0.f);
      if (gr < M) v = ((const float4*)&A[(size_t)gr * K + k0])[kq];
      ((float4*)&sA[r][0])[kq] = v;
    }
    __syncthreads();
    const float* ap = &sA[wave * 8][0];
    for (int kk = 0; kk < kc; kk += 2) {
      float2 w0 = *(const float2*)&sW[kk][lane2];
      float2 w1 = *(const float2*)&sW[kk + 1][lane2];
#pragma unroll
      for (int r = 0; r < 8; ++r) {
        float2 av = *(const float2*)&ap[r * 64 + kk];   // wave-uniform broadcast read
        acc[r][0] += av.x * w0.x + av.y * w1.x;
        acc[r][1] += av.x * w0.y + av.y * w1.y;
      }
    }
  }
  float2 bv = *(const float2*)&bias[lane2];
#pragma unroll
  for (int r = 0; r < 8; ++r) {
    int gr = row0 + wave * 8 + r;
    if (gr < M) {
      *(float2*)&out[(size_t)gr * 128 + lane2] = make_float2(acc[r][0] + bv.x, acc[r][1] + bv.y);
    }
  }
}

// ---------------- layer-1 aggregation + LeakyReLU + L2 normalize ----------------
// one wave per destination row; lane covers 2 of 128 cols.

__global__ __launch_bounds__(256) void k_agg_norm(const float* __restrict__ support,
                                                  const int* __restrict__ row_ptr,
                                                  const int* __restrict__ esrc,
                                                  const float* __restrict__ ew,
                                                  float* __restrict__ out, int N) {
  int wv = blockIdx.x * 4 + (threadIdx.x >> 6);
  if (wv >= N) return;
  int row = __builtin_amdgcn_readfirstlane(wv);   // force SGPR -> scalar loads in loop
  int lane2 = (threadIdx.x & 63) * 2;
  int s = row_ptr[row], e = row_ptr[row + 1];
  float ax = 0.f, ay = 0.f;
  for (int j = s; j < e; ++j) {
    int src = esrc[j];
    float w = ew[j];
    float2 v = *(const float2*)&support[(size_t)src * 128 + lane2];
    ax += w * v.x;
    ay += w * v.y;
  }
  ax = ax > 0.f ? ax : LEAKY_SLOPE * ax;
  ay = ay > 0.f ? ay : LEAKY_SLOPE * ay;
  float ss = ax * ax + ay * ay;
#pragma unroll
  for (int m = 1; m < 64; m <<= 1) ss += __shfl_xor(ss, m, 64);
  float inv = 1.0f / fmaxf(sqrtf(ss), 1e-12f);
  *(float2*)&out[(size_t)row * 128 + lane2] = make_float2(ax * inv, ay * inv);
}

// ---------------- layer-2: zero labeled rows, atomic hit aggregation, final ----------------

__global__ __launch_bounds__(256) void k_zero_rows(const int* __restrict__ lidx,
                                                   float* __restrict__ buf, int L) {
  int wv = blockIdx.x * 4 + (threadIdx.x >> 6);
  if (wv >= L) return;
  int row = lidx[wv];
  int lane2 = (threadIdx.x & 63) * 2;
  *(float2*)&buf[(size_t)row * 128 + lane2] = make_float2(0.f, 0.f);
}

__global__ __launch_bounds__(256) void k_hit_agg(const float* __restrict__ support,
                                                 const int* __restrict__ hsrc,
                                                 const int* __restrict__ hpack,
                                                 const int* __restrict__ deg2,
                                                 const float* __restrict__ a_soft,
                                                 const int* __restrict__ counter,
                                                 float* __restrict__ out, int N) {
  int lane2 = (threadIdx.x & 63) * 2;
  int wv = blockIdx.x * 4 + (threadIdx.x >> 6);
  int nw = gridDim.x * 4;
  int cnt = counter[0];
  for (int i = wv; i < cnt; i += nw) {
    int src = hsrc[i], pk = hpack[i];
    int rel = pk >> 20, d = pk & 0xFFFFF;
    float w = a_soft[3 + rel] / (float)deg2[rel * N + d];
    float2 v = *(const float2*)&support[(size_t)src * 128 + lane2];
    atomicAdd(&out[(size_t)d * 128 + lane2], w * v.x);
    atomicAdd(&out[(size_t)d * 128 + lane2 + 1], w * v.y);
  }
}

__global__ __launch_bounds__(256) void k_final(const float* __restrict__ buf,
                                               const int* __restrict__ lidx,
                                               float* __restrict__ out, int L) {
  int wv = blockIdx.x * 4 + (threadIdx.x >> 6);
  if (wv >= L) return;
  int row = lidx[wv];
  int lane2 = (threadIdx.x & 63) * 2;
  float2 v = *(const float2*)&buf[(size_t)row * 128 + lane2];
  float ax = v.x > 0.f ? v.x : LEAKY_SLOPE * v.x;
  float ay = v.y > 0.f ? v.y : LEAKY_SLOPE * v.y;
  float ss = ax * ax + ay * ay;
#pragma unroll
  for (int m = 1; m < 64; m <<= 1) ss += __shfl_xor(ss, m, 64);
  float inv = 1.0f / fmaxf(sqrtf(ss), 1e-12f);
  *(float2*)&out[(size_t)wv * 128 + lane2] = make_float2(ax * inv, ay * inv);
}

// ---------------- host ----------------

extern "C" void kernel_launch(void* const* d_in, const int* in_sizes, int n_in,
                              void* d_out, int out_size, void* d_ws, size_t ws_size,
                              hipStream_t stream) {
  const float* feat  = (const float*)d_in[0];
  const float* w1    = (const float*)d_in[1];
  const float* b1    = (const float*)d_in[2];
  const float* w2    = (const float*)d_in[3];
  const float* b2    = (const float*)d_in[4];
  const float* a_att = (const float*)d_in[5];
  const float* r_att = (const float*)d_in[6];
  const int* rows    = (const int*)d_in[7];
  const int* cols    = (const int*)d_in[8];
  const int* lidx    = (const int*)d_in[9];

  const int F = 128;
  int K1 = in_sizes[1] / F;        // 300
  int N  = in_sizes[0] / K1;       // 50000
  int E  = in_sizes[7] / 3;        // 800000
  int L  = in_sizes[9];            // 1000
  float* outp = (float*)d_out;
  (void)n_in; (void)out_size; (void)ws_size;

  char* base = (char*)d_ws;
  size_t off = 0;
  auto take = [&](size_t bytes) -> void* {
    size_t cur = (off + 255) & ~(size_t)255;
    off = cur + bytes;
    return (void*)(base + cur);
  };
  float* bufA  = (float*)take((size_t)N * F * 4);       // support1 / support2
  float* bufB  = (float*)take((size_t)N * F * 4);       // h1 / out2
  int*   esrc  = (int*)take((size_t)3 * E * 4);
  float* ew    = (float*)take((size_t)3 * E * 4);
  int*   hsrc  = (int*)take((size_t)3 * E * 4);
  int*   hpack = (int*)take((size_t)3 * E * 4);
  int nb = (N + 31) / 32;
  int zn = 3 * N + 3 * N + nb + 1;                      // contiguous zero region
  int* deg1 = (int*)take((size_t)zn * 4);
  int* deg2 = deg1 + 3 * N;
  unsigned* bm = (unsigned*)(deg2 + 3 * N);
  int* counter = (int*)(bm + nb);
  int* row_ptr  = (int*)take((size_t)(N + 1) * 4);
  int* fill_pos = (int*)take((size_t)N * 4);
  float* a_soft = (float*)take(64);
  int* chunk_sums = (int*)take(256);
  int* chunk_offs = (int*)take(256);

  int nchunks = (N + 1023) / 1024;

  hipLaunchKernelGGL(k_zero, dim3((zn + 255) / 256), dim3(256), 0, stream, deg1, zn);
  hipLaunchKernelGGL(k_softmax3, dim3(1), dim3(64), 0, stream, a_att, r_att, a_soft);
  hipLaunchKernelGGL(k_bitmap, dim3((L + 255) / 256), dim3(256), 0, stream, lidx, bm, L);
  hipLaunchKernelGGL(k_edge_scan, dim3((E + 255) / 256, 3), dim3(256), 0, stream,
                     rows, cols, deg1, deg2, bm, hsrc, hpack, counter, N, E);
  hipLaunchKernelGGL(k_gemm_bias, dim3((N + 31) / 32), dim3(256), 0, stream,
                     feat, w1, b1, bufA, N, K1);
  hipLaunchKernelGGL(k_scan1, dim3(nchunks), dim3(256), 0, stream, deg1, row_ptr, chunk_sums, N);
  hipLaunchKernelGGL(k_scan2, dim3(1), dim3(64), 0, stream, chunk_sums, chunk_offs, nchunks, row_ptr, N);
  hipLaunchKernelGGL(k_scan3, dim3((N + 255) / 256), dim3(256), 0, stream, row_ptr, chunk_offs, fill_pos, N);
  hipLaunchKernelGGL(k_scatter, dim3((E + 255) / 256, 3), dim3(256), 0, stream,
                     rows, cols, a_soft, deg1, fill_pos, esrc, ew, N, E);
  hipLaunchKernelGGL(k_agg_norm, dim3((N + 3) / 4), dim3(256), 0, stream,
                     bufA, row_ptr, esrc, ew, bufB, N);
  hipLaunchKernelGGL(k_gemm_bias, dim3((N + 31) / 32), dim3(256), 0, stream,
                     bufB, w2, b2, bufA, N, F);
  hipLaunchKernelGGL(k_zero_rows, dim3((L + 3) / 4), dim3(256), 0, stream, lidx, bufB, L);
  hipLaunchKernelGGL(k_hit_agg, dim3(512), dim3(256), 0, stream,
                     bufA, hsrc, hpack, deg2, a_soft, counter, bufB, N);
  hipLaunchKernelGGL(k_final, dim3((L + 3) / 4), dim3(256), 0, stream, bufB, lidx, outp, L);
}

// Round 2
// 1204.451 us; speedup vs baseline: 1.4186x; 1.4186x over previous
//
#include <hip/hip_runtime.h>

#define LEAKY_SLOPE 0.2f

// ---------------- utility kernels ----------------

__global__ __launch_bounds__(256) void k_zero(int* __restrict__ p, int n) {
  int i = blockIdx.x * 256 + threadIdx.x;
  if (i < n) p[i] = 0;
}

__global__ __launch_bounds__(64) void k_softmax3(const float* __restrict__ a_att,
                                                 const float* __restrict__ r_att,
                                                 float* __restrict__ a_soft) {
  if (threadIdx.x == 0) {
    float m = fmaxf(fmaxf(a_att[0], a_att[1]), a_att[2]);
    float e0 = expf(a_att[0] - m), e1 = expf(a_att[1] - m), e2 = expf(a_att[2] - m);
    float s = 1.0f / (e0 + e1 + e2);
    a_soft[0] = e0 * s; a_soft[1] = e1 * s; a_soft[2] = e2 * s;
    m = fmaxf(fmaxf(r_att[0], r_att[1]), r_att[2]);
    e0 = expf(r_att[0] - m); e1 = expf(r_att[1] - m); e2 = expf(r_att[2] - m);
    s = 1.0f / (e0 + e1 + e2);
    a_soft[3] = e0 * s; a_soft[4] = e1 * s; a_soft[5] = e2 * s;
  }
}

__global__ __launch_bounds__(256) void k_bitmap(const int* __restrict__ lidx,
                                                unsigned* __restrict__ bm, int L) {
  int i = blockIdx.x * 256 + threadIdx.x;
  if (i < L) {
    int n = lidx[i];
    atomicOr(&bm[n >> 5], 1u << (n & 31));
  }
}

// Count layer-1 in-degrees for all edges; for edges whose layer-2 destination
// (col) is a labeled node, also count deg2 and append to the hit list.
// Hit-list allocation is BLOCK-aggregated: one device atomic per block instead
// of one per hit (single-address atomic-with-return serializes at ~20ns each).
__global__ __launch_bounds__(256) void k_edge_scan(const int* __restrict__ rows,
                                                   const int* __restrict__ cols,
                                                   int* __restrict__ deg1, int* __restrict__ deg2,
                                                   const unsigned* __restrict__ bm,
                                                   int* __restrict__ hsrc, int* __restrict__ hpack,
                                                   int* __restrict__ counter, int N, int E) {
  __shared__ int s_src[256];
  __shared__ int s_pack[256];
  __shared__ int s_cnt;
  __shared__ int s_base;
  int tid = threadIdx.x;
  if (tid == 0) s_cnt = 0;
  __syncthreads();
  int e = blockIdx.x * 256 + tid;
  int rel = blockIdx.y;
  if (e < E) {
    int r = rows[rel * E + e];   // layer-1 dest / layer-2 src
    int c = cols[rel * E + e];   // layer-1 src / layer-2 dest
    atomicAdd(&deg1[rel * N + r], 1);
    if ((bm[c >> 5] >> (c & 31)) & 1u) {
      atomicAdd(&deg2[rel * N + c], 1);
      int p = atomicAdd(&s_cnt, 1);          // LDS atomic, on-CU, fast
      s_src[p] = r;
      s_pack[p] = (rel << 20) | c;           // N=50000 < 2^20
    }
  }
  __syncthreads();
  int cnt = s_cnt;
  if (tid == 0 && cnt > 0) s_base = atomicAdd(counter, cnt);  // one per block
  __syncthreads();
  if (tid < cnt) {
    int b = s_base;
    hsrc[b + tid] = s_src[tid];
    hpack[b + tid] = s_pack[tid];
  }
}

// ---------------- prefix sum (3 kernels) ----------------

__global__ __launch_bounds__(256) void k_scan1(const int* __restrict__ deg1,
                                               int* __restrict__ row_ptr,
                                               int* __restrict__ chunk_sums, int N) {
  __shared__ int sd[256];
  int tid = threadIdx.x;
  int n0 = blockIdx.x * 1024 + tid * 4;
  int v[4];
#pragma unroll
  for (int i = 0; i < 4; ++i) {
    int n = n0 + i;
    v[i] = (n < N) ? (deg1[n] + deg1[N + n] + deg1[2 * N + n]) : 0;
  }
  sd[tid] = v[0] + v[1] + v[2] + v[3];
  __syncthreads();
  for (int off = 1; off < 256; off <<= 1) {
    int t = (tid >= off) ? sd[tid - off] : 0;
    __syncthreads();
    sd[tid] += t;
    __syncthreads();
  }
  int run = tid ? sd[tid - 1] : 0;
#pragma unroll
  for (int i = 0; i < 4; ++i) {
    int n = n0 + i;
    if (n < N) row_ptr[n] = run;
    run += v[i];
  }
  if (tid == 255) chunk_sums[blockIdx.x] = sd[255];
}

__global__ __launch_bounds__(64) void k_scan2(const int* __restrict__ chunk_sums,
                                              int* __restrict__ chunk_offs,
                                              int nchunks, int* __restrict__ row_ptr, int N) {
  int lane = threadIdx.x;
  int mine = (lane < nchunks) ? chunk_sums[lane] : 0;
  int v = mine;
  for (int off = 1; off < 64; off <<= 1) {
    int t = __shfl_up(v, off, 64);
    if (lane >= off) v += t;
  }
  if (lane < nchunks) chunk_offs[lane] = v - mine;
  int total = __shfl(v, nchunks - 1, 64);
  if (lane == 0) row_ptr[N] = total;
}

__global__ __launch_bounds__(256) void k_scan3(int* __restrict__ row_ptr,
                                               const int* __restrict__ chunk_offs,
                                               int* __restrict__ fill_pos, int N) {
  int n = blockIdx.x * 256 + threadIdx.x;
  if (n < N) {
    int val = row_ptr[n] + chunk_offs[n >> 10];
    row_ptr[n] = val;
    fill_pos[n] = val;
  }
}

// ---------------- CSR scatter (combined over relations, keyed by dest) ----------------

__global__ __launch_bounds__(256) void k_scatter(const int* __restrict__ rows,
                                                 const int* __restrict__ cols,
                                                 const float* __restrict__ a_soft,
                                                 const int* __restrict__ deg1,
                                                 int* __restrict__ fill_pos,
                                                 int* __restrict__ esrc, float* __restrict__ ew,
                                                 int N, int E) {
  int e = blockIdx.x * 256 + threadIdx.x;
  int rel = blockIdx.y;
  if (e >= E) return;
  int d = rows[rel * E + e], s = cols[rel * E + e];
  int pos = atomicAdd(&fill_pos[d], 1);
  esrc[pos] = s;
  ew[pos] = a_soft[rel] / (float)deg1[rel * N + d];   // deg>=1 since edge exists
}

// ---------------- dense GEMM: out[M][128] = A[M][K] @ W[K][128] + bias ----------------
// 256 threads = 4 waves; wave handles 8 rows, lane handles 2 cols -> 32x128 per block.

__global__ __launch_bounds__(256) void k_gemm_bias(const float* __restrict__ A,
                                                   const float* __restrict__ W,
                                                   const float* __restrict__ bias,
                                                   float* __restrict__ out, int M, int K) {
  __shared__ float sW[64][128];   // 32 KB
  __shared__ float sA[32][64];    // 8 KB
  int tid = threadIdx.x;
  int wave = tid >> 6, lane = tid & 63;
  int lane2 = lane * 2;
  int row0 = blockIdx.x * 32;
  float acc[8][2] = {};
  for (int k0 = 0; k0 < K; k0 += 64) {       // K=300 -> 64,64,64,64,44 (all even, %4==0)
    int kc = min(64, K - k0);
    __syncthreads();
    for (int i = tid; i < kc * 32; i += 256) {
      int kk = i >> 5, c4 = i & 31;
      ((float4*)&sW[kk][0])[c4] = ((const float4*)&W[(size_t)(k0 + kk) * 128])[c4];
    }
    int kq4 = kc >> 2;
    for (int i = tid; i < 32 * kq4; i += 256) {
      int r = i / kq4, kq = i - r * kq4;
      int gr = row0 + r;
      float4 v = make_float4(0.f, 0.f, 0.f, 0.f);
      if (gr < M) v = ((const float4*)&A[(size_t)gr * K + k0])[kq];
      ((float4*)&sA[r][0])[kq] = v;
    }
    __syncthreads();
    const float* ap = &sA[wave * 8][0];
    for (int kk = 0; kk < kc; kk += 2) {
      float2 w0 = *(const float2*)&sW[kk][lane2];
      float2 w1 = *(const float2*)&sW[kk + 1][lane2];
#pragma unroll
      for (int r = 0; r < 8; ++r) {
        float2 av = *(const float2*)&ap[r * 64 + kk];   // wave-uniform broadcast read
        acc[r][0] += av.x * w0.x + av.y * w1.x;
        acc[r][1] += av.x * w0.y + av.y * w1.y;
      }
    }
  }
  float2 bv = *(const float2*)&bias[lane2];
#pragma unroll
  for (int r = 0; r < 8; ++r) {
    int gr = row0 + wave * 8 + r;
    if (gr < M) {
      *(float2*)&out[(size_t)gr * 128 + lane2] = make_float2(acc[r][0] + bv.x, acc[r][1] + bv.y);
    }
  }
}

// ---------------- layer-1 aggregation + LeakyReLU + L2 normalize ----------------
// one wave per destination row; lane covers 2 of 128 cols.

__global__ __launch_bounds__(256) void k_agg_norm(const float* __restrict__ support,
                                                  const int* __restrict__ row_ptr,
                                                  const int* __restrict__ esrc,
                                                  const float* __restrict__ ew,
                                                  float* __restrict__ out, int N) {
  int wv = blockIdx.x * 4 + (threadIdx.x >> 6);
  if (wv >= N) return;
  int row = __builtin_amdgcn_readfirstlane(wv);   // force SGPR -> scalar loads in loop
  int lane2 = (threadIdx.x & 63) * 2;
  int s = row_ptr[row], e = row_ptr[row + 1];
  float ax = 0.f, ay = 0.f;
  for (int j = s; j < e; ++j) {
    int src = esrc[j];
    float w = ew[j];
    float2 v = *(const float2*)&support[(size_t)src * 128 + lane2];
    ax += w * v.x;
    ay += w * v.y;
  }
  ax = ax > 0.f ? ax : LEAKY_SLOPE * ax;
  ay = ay > 0.f ? ay : LEAKY_SLOPE * ay;
  float ss = ax * ax + ay * ay;
#pragma unroll
  for (int m = 1; m < 64; m <<= 1) ss += __shfl_xor(ss, m, 64);
  float inv = 1.0f / fmaxf(sqrtf(ss), 1e-12f);
  *(float2*)&out[(size_t)row * 128 + lane2] = make_float2(ax * inv, ay * inv);
}

// ---------------- layer-2: zero labeled rows, atomic hit aggregation, final ----------------

__global__ __launch_bounds__(256) void k_zero_rows(const int* __restrict__ lidx,
                                                   float* __restrict__ buf, int L) {
  int wv = blockIdx.x * 4 + (threadIdx.x >> 6);
  if (wv >= L) return;
  int row = lidx[wv];
  int lane2 = (threadIdx.x & 63) * 2;
  *(float2*)&buf[(size_t)row * 128 + lane2] = make_float2(0.f, 0.f);
}

__global__ __launch_bounds__(256) void k_hit_agg(const float* __restrict__ support,
                                                 const int* __restrict__ hsrc,
                                                 const int* __restrict__ hpack,
                                                 const int* __restrict__ deg2,
                                                 const float* __restrict__ a_soft,
                                                 const int* __restrict__ counter,
                                                 float* __restrict__ out, int N) {
  int lane2 = (threadIdx.x & 63) * 2;
  int wv = blockIdx.x * 4 + (threadIdx.x >> 6);
  int nw = gridDim.x * 4;
  int cnt = counter[0];
  for (int i = wv; i < cnt; i += nw) {
    int src = hsrc[i], pk = hpack[i];
    int rel = pk >> 20, d = pk & 0xFFFFF;
    float w = a_soft[3 + rel] / (float)deg2[rel * N + d];
    float2 v = *(const float2*)&support[(size_t)src * 128 + lane2];
    atomicAdd(&out[(size_t)d * 128 + lane2], w * v.x);
    atomicAdd(&out[(size_t)d * 128 + lane2 + 1], w * v.y);
  }
}

__global__ __launch_bounds__(256) void k_final(const float* __restrict__ buf,
                                               const int* __restrict__ lidx,
                                               float* __restrict__ out, int L) {
  int wv = blockIdx.x * 4 + (threadIdx.x >> 6);
  if (wv >= L) return;
  int row = lidx[wv];
  int lane2 = (threadIdx.x & 63) * 2;
  float2 v = *(const float2*)&buf[(size_t)row * 128 + lane2];
  float ax = v.x > 0.f ? v.x : LEAKY_SLOPE * v.x;
  float ay = v.y > 0.f ? v.y : LEAKY_SLOPE * v.y;
  float ss = ax * ax + ay * ay;
#pragma unroll
  for (int m = 1; m < 64; m <<= 1) ss += __shfl_xor(ss, m, 64);
  float inv = 1.0f / fmaxf(sqrtf(ss), 1e-12f);
  *(float2*)&out[(size_t)wv * 128 + lane2] = make_float2(ax * inv, ay * inv);
}

// ---------------- host ----------------

extern "C" void kernel_launch(void* const* d_in, const int* in_sizes, int n_in,
                              void* d_out, int out_size, void* d_ws, size_t ws_size,
                              hipStream_t stream) {
  const float* feat  = (const float*)d_in[0];
  const float* w1    = (const float*)d_in[1];
  const float* b1    = (const float*)d_in[2];
  const float* w2    = (const float*)d_in[3];
  const float* b2    = (const float*)d_in[4];
  const float* a_att = (const float*)d_in[5];
  const float* r_att = (const float*)d_in[6];
  const int* rows    = (const int*)d_in[7];
  const int* cols    = (const int*)d_in[8];
  const int* lidx    = (const int*)d_in[9];

  const int F = 128;
  int K1 = in_sizes[1] / F;        // 300
  int N  = in_sizes[0] / K1;       // 50000
  int E  = in_sizes[7] / 3;        // 800000
  int L  = in_sizes[9];            // 1000
  float* outp = (float*)d_out;
  (void)n_in; (void)out_size; (void)ws_size;

  char* base = (char*)d_ws;
  size_t off = 0;
  auto take = [&](size_t bytes) -> void* {
    size_t cur = (off + 255) & ~(size_t)255;
    off = cur + bytes;
    return (void*)(base + cur);
  };
  float* bufA  = (float*)take((size_t)N * F * 4);       // support1 / support2
  float* bufB  = (float*)take((size_t)N * F * 4);       // h1 / out2
  int*   esrc  = (int*)take((size_t)3 * E * 4);
  float* ew    = (float*)take((size_t)3 * E * 4);
  int*   hsrc  = (int*)take((size_t)3 * E * 4);
  int*   hpack = (int*)take((size_t)3 * E * 4);
  int nb = (N + 31) / 32;
  int zn = 3 * N + 3 * N + nb + 1;                      // contiguous zero region
  int* deg1 = (int*)take((size_t)zn * 4);
  int* deg2 = deg1 + 3 * N;
  unsigned* bm = (unsigned*)(deg2 + 3 * N);
  int* counter = (int*)(bm + nb);
  int* row_ptr  = (int*)take((size_t)(N + 1) * 4);
  int* fill_pos = (int*)take((size_t)N * 4);
  float* a_soft = (float*)take(64);
  int* chunk_sums = (int*)take(256);
  int* chunk_offs = (int*)take(256);

  int nchunks = (N + 1023) / 1024;

  hipLaunchKernelGGL(k_zero, dim3((zn + 255) / 256), dim3(256), 0, stream, deg1, zn);
  hipLaunchKernelGGL(k_softmax3, dim3(1), dim3(64), 0, stream, a_att, r_att, a_soft);
  hipLaunchKernelGGL(k_bitmap, dim3((L + 255) / 256), dim3(256), 0, stream, lidx, bm, L);
  hipLaunchKernelGGL(k_edge_scan, dim3((E + 255) / 256, 3), dim3(256), 0, stream,
                     rows, cols, deg1, deg2, bm, hsrc, hpack, counter, N, E);
  hipLaunchKernelGGL(k_gemm_bias, dim3((N + 31) / 32), dim3(256), 0, stream,
                     feat, w1, b1, bufA, N, K1);
  hipLaunchKernelGGL(k_scan1, dim3(nchunks), dim3(256), 0, stream, deg1, row_ptr, chunk_sums, N);
  hipLaunchKernelGGL(k_scan2, dim3(1), dim3(64), 0, stream, chunk_sums, chunk_offs, nchunks, row_ptr, N);
  hipLaunchKernelGGL(k_scan3, dim3((N + 255) / 256), dim3(256), 0, stream, row_ptr, chunk_offs, fill_pos, N);
  hipLaunchKernelGGL(k_scatter, dim3((E + 255) / 256, 3), dim3(256), 0, stream,
                     rows, cols, a_soft, deg1, fill_pos, esrc, ew, N, E);
  hipLaunchKernelGGL(k_agg_norm, dim3((N + 3) / 4), dim3(256), 0, stream,
                     bufA, row_ptr, esrc, ew, bufB, N);
  hipLaunchKernelGGL(k_gemm_bias, dim3((N + 31) / 32), dim3(256), 0, stream,
                     bufB, w2, b2, bufA, N, F);
  hipLaunchKernelGGL(k_zero_rows, dim3((L + 3) / 4), dim3(256), 0, stream, lidx, bufB, L);
  hipLaunchKernelGGL(k_hit_agg, dim3(512), dim3(256), 0, stream,
                     bufA, hsrc, hpack, deg2, a_soft, counter, bufB, N);
  hipLaunchKernelGGL(k_final, dim3((L + 3) / 4), dim3(256), 0, stream, bufB, lidx, outp, L);
}

// Round 3
// 557.976 us; speedup vs baseline: 3.0623x; 2.1586x over previous
//
#include <hip/hip_runtime.h>

#define LEAKY_SLOPE 0.2f
#define HIST_C 48          // chunks per relation for privatized histogram
#define HIST_THREADS 1024

// ---------------- utility kernels ----------------

__global__ __launch_bounds__(256) void k_zero(int* __restrict__ p, int n) {
  int i = blockIdx.x * 256 + threadIdx.x;
  if (i < n) p[i] = 0;
}

__global__ __launch_bounds__(64) void k_softmax3(const float* __restrict__ a_att,
                                                 const float* __restrict__ r_att,
                                                 float* __restrict__ a_soft) {
  if (threadIdx.x == 0) {
    float m = fmaxf(fmaxf(a_att[0], a_att[1]), a_att[2]);
    float e0 = expf(a_att[0] - m), e1 = expf(a_att[1] - m), e2 = expf(a_att[2] - m);
    float s = 1.0f / (e0 + e1 + e2);
    a_soft[0] = e0 * s; a_soft[1] = e1 * s; a_soft[2] = e2 * s;
    m = fmaxf(fmaxf(r_att[0], r_att[1]), r_att[2]);
    e0 = expf(r_att[0] - m); e1 = expf(r_att[1] - m); e2 = expf(r_att[2] - m);
    s = 1.0f / (e0 + e1 + e2);
    a_soft[3] = e0 * s; a_soft[4] = e1 * s; a_soft[5] = e2 * s;
  }
}

__global__ __launch_bounds__(256) void k_bitmap(const int* __restrict__ lidx,
                                                unsigned* __restrict__ bm, int L) {
  int i = blockIdx.x * 256 + threadIdx.x;
  if (i < L) {
    int n = lidx[i];
    atomicOr(&bm[n >> 5], 1u << (n & 31));
  }
}

// ---------------- LDS-privatized histogram + rank assignment ----------------
// grid (HIST_C, 3). Each block histograms one edge-chunk of one relation into a
// packed-u16 LDS array (2 nodes per u32 word). The LDS atomic's return value is
// the edge's local rank (saved to rank16). Block's histogram copy is written to
// global coalesced -> ZERO random global atomics for degree counting.
// Also does the layer-2 labeled-hit detection (deg2 + block-aggregated hit list).
__global__ __launch_bounds__(HIST_THREADS) void k_hist(const int* __restrict__ rows,
                                                       const int* __restrict__ cols,
                                                       const unsigned* __restrict__ bm,
                                                       int* __restrict__ deg2,
                                                       int* __restrict__ counter,
                                                       int* __restrict__ hsrc, int* __restrict__ hpack,
                                                       unsigned short* __restrict__ rank16,
                                                       unsigned* __restrict__ histw,
                                                       int N, int E, int chunk) {
  extern __shared__ unsigned sh[];
  int WN = (N + 1) >> 1;
  unsigned* hist = sh;                       // WN words (packed u16 pair)
  int* s_src = (int*)(sh + WN);              // [HIST_THREADS]
  int* s_pack = s_src + HIST_THREADS;        // [HIST_THREADS]
  int* s_meta = s_pack + HIST_THREADS;       // [0]=cnt [1]=base
  int tid = threadIdx.x;
  int cidx = blockIdx.x, rel = blockIdx.y;

  for (int i = tid; i < WN; i += HIST_THREADS) hist[i] = 0;
  __syncthreads();

  int estart = cidx * chunk;
  int eend = min(estart + chunk, E);
  for (int eb = estart; eb < eend; eb += HIST_THREADS) {
    if (tid == 0) s_meta[0] = 0;
    __syncthreads();
    int e = eb + tid;
    if (e < eend) {
      int r = rows[rel * E + e];   // layer-1 dest / layer-2 src
      int c = cols[rel * E + e];   // layer-1 src / layer-2 dest
      unsigned old = atomicAdd(&hist[r >> 1], 1u << (16 * (r & 1)));
      rank16[rel * E + e] = (unsigned short)((old >> (16 * (r & 1))) & 0xFFFFu);
      if ((bm[c >> 5] >> (c & 31)) & 1u) {
        atomicAdd(&deg2[rel * N + c], 1);
        int p = atomicAdd(&s_meta[0], 1);
        s_src[p] = r;
        s_pack[p] = (rel << 20) | c;         // N < 2^20
      }
    }
    __syncthreads();
    int cnt = s_meta[0];
    if (tid == 0 && cnt > 0) s_meta[1] = atomicAdd(counter, cnt);
    __syncthreads();
    if (tid < cnt) {
      int b = s_meta[1];
      hsrc[b + tid] = s_src[tid];
      hpack[b + tid] = s_pack[tid];
    }
    __syncthreads();
  }
  // write out this block's histogram copy (coalesced, non-atomic)
  unsigned* dst = &histw[(size_t)(rel * HIST_C + cidx) * WN];
  for (int i = tid; i < WN; i += HIST_THREADS) dst[i] = hist[i];
}

// ---------------- reduce copies -> in-place absolute bases + inv-weights ----------------
// One thread per node PAIR. For each (rel, chunk) the packed count word is
// replaced in place by the packed absolute base-within-row (rel prefix folded in).
// Also emits inv1[rel][d] = a_soft[rel]/deg and rowdeg[d] for the row_ptr scan.
__global__ __launch_bounds__(256) void k_reduce(unsigned* __restrict__ histw,
                                                const float* __restrict__ a_soft,
                                                float* __restrict__ inv1,
                                                int* __restrict__ rowdeg, int N) {
  int WN = (N + 1) >> 1;
  int t = blockIdx.x * 256 + threadIdx.x;
  if (t >= WN) return;
  int d0 = 2 * t, d1 = 2 * t + 1;
  int tot0 = 0, tot1 = 0;
#pragma unroll
  for (int rel = 0; rel < 3; ++rel) {
    int run0 = tot0, run1 = tot1;
    for (int c = 0; c < HIST_C; ++c) {
      size_t idx = (size_t)(rel * HIST_C + c) * WN + t;
      unsigned w = histw[idx];
      histw[idx] = (unsigned)(run0 & 0xFFFF) | ((unsigned)(run1 & 0xFFFF) << 16);
      run0 += (int)(w & 0xFFFFu);
      run1 += (int)(w >> 16);
    }
    int dg0 = run0 - tot0, dg1 = run1 - tot1;
    float a = a_soft[rel];
    inv1[rel * N + d0] = a / (float)max(dg0, 1);
    if (d1 < N) inv1[rel * N + d1] = a / (float)max(dg1, 1);
    tot0 = run0; tot1 = run1;
  }
  rowdeg[d0] = tot0;
  if (d1 < N) rowdeg[d1] = tot1;
}

// ---------------- prefix sum over rowdeg (3 kernels) ----------------

__global__ __launch_bounds__(256) void k_scan1(const int* __restrict__ rowdeg,
                                               int* __restrict__ row_ptr,
                                               int* __restrict__ chunk_sums, int N) {
  __shared__ int sd[256];
  int tid = threadIdx.x;
  int n0 = blockIdx.x * 1024 + tid * 4;
  int v[4];
#pragma unroll
  for (int i = 0; i < 4; ++i) {
    int n = n0 + i;
    v[i] = (n < N) ? rowdeg[n] : 0;
  }
  sd[tid] = v[0] + v[1] + v[2] + v[3];
  __syncthreads();
  for (int off = 1; off < 256; off <<= 1) {
    int t = (tid >= off) ? sd[tid - off] : 0;
    __syncthreads();
    sd[tid] += t;
    __syncthreads();
  }
  int run = tid ? sd[tid - 1] : 0;
#pragma unroll
  for (int i = 0; i < 4; ++i) {
    int n = n0 + i;
    if (n < N) row_ptr[n] = run;
    run += v[i];
  }
  if (tid == 255) chunk_sums[blockIdx.x] = sd[255];
}

__global__ __launch_bounds__(64) void k_scan2(const int* __restrict__ chunk_sums,
                                              int* __restrict__ chunk_offs,
                                              int nchunks, int* __restrict__ row_ptr, int N) {
  int lane = threadIdx.x;
  int mine = (lane < nchunks) ? chunk_sums[lane] : 0;
  int v = mine;
  for (int off = 1; off < 64; off <<= 1) {
    int t = __shfl_up(v, off, 64);
    if (lane >= off) v += t;
  }
  if (lane < nchunks) chunk_offs[lane] = v - mine;
  int total = __shfl(v, nchunks - 1, 64);
  if (lane == 0) row_ptr[N] = total;
}

__global__ __launch_bounds__(256) void k_scan3(int* __restrict__ row_ptr,
                                               const int* __restrict__ chunk_offs, int N) {
  int n = blockIdx.x * 256 + threadIdx.x;
  if (n < N) row_ptr[n] += chunk_offs[n >> 10];
}

// ---------------- atomic-free scatter: pos = row_ptr + base + rank ----------------

__global__ __launch_bounds__(256) void k_scatter(const int* __restrict__ rows,
                                                 const int* __restrict__ cols,
                                                 const int* __restrict__ row_ptr,
                                                 const unsigned* __restrict__ histw,
                                                 const unsigned short* __restrict__ rank16,
                                                 unsigned* __restrict__ esrc,
                                                 int N, int E, int chunk) {
  int e = blockIdx.x * 256 + threadIdx.x;
  int rel = blockIdx.y;
  if (e >= E) return;
  int WN = (N + 1) >> 1;
  int d = rows[rel * E + e];
  int s = cols[rel * E + e];
  int c = e / chunk;
  const unsigned short* cb = (const unsigned short*)histw;
  int pos = row_ptr[d] + (int)cb[(size_t)(rel * HIST_C + c) * (2 * WN) + d]
          + (int)rank16[rel * E + e];
  esrc[pos] = ((unsigned)rel << 16) | (unsigned)s;   // src < 2^16
}

// ---------------- dense GEMM: out[M][128] = A[M][K] @ W[K][128] + bias ----------------

__global__ __launch_bounds__(256) void k_gemm_bias(const float* __restrict__ A,
                                                   const float* __restrict__ W,
                                                   const float* __restrict__ bias,
                                                   float* __restrict__ out, int M, int K) {
  __shared__ float sW[64][128];   // 32 KB
  __shared__ float sA[32][64];    // 8 KB
  int tid = threadIdx.x;
  int wave = tid >> 6, lane = tid & 63;
  int lane2 = lane * 2;
  int row0 = blockIdx.x * 32;
  float acc[8][2] = {};
  for (int k0 = 0; k0 < K; k0 += 64) {
    int kc = min(64, K - k0);
    __syncthreads();
    for (int i = tid; i < kc * 32; i += 256) {
      int kk = i >> 5, c4 = i & 31;
      ((float4*)&sW[kk][0])[c4] = ((const float4*)&W[(size_t)(k0 + kk) * 128])[c4];
    }
    int kq4 = kc >> 2;
    for (int i = tid; i < 32 * kq4; i += 256) {
      int r = i / kq4, kq = i - r * kq4;
      int gr = row0 + r;
      float4 v = make_float4(0.f, 0.f, 0.f, 0.f);
      if (gr < M) v = ((const float4*)&A[(size_t)gr * K + k0])[kq];
      ((float4*)&sA[r][0])[kq] = v;
    }
    __syncthreads();
    const float* ap = &sA[wave * 8][0];
    for (int kk = 0; kk < kc; kk += 2) {
      float2 w0 = *(const float2*)&sW[kk][lane2];
      float2 w1 = *(const float2*)&sW[kk + 1][lane2];
#pragma unroll
      for (int r = 0; r < 8; ++r) {
        float2 av = *(const float2*)&ap[r * 64 + kk];
        acc[r][0] += av.x * w0.x + av.y * w1.x;
        acc[r][1] += av.x * w0.y + av.y * w1.y;
      }
    }
  }
  float2 bv = *(const float2*)&bias[lane2];
#pragma unroll
  for (int r = 0; r < 8; ++r) {
    int gr = row0 + wave * 8 + r;
    if (gr < M) {
      *(float2*)&out[(size_t)gr * 128 + lane2] = make_float2(acc[r][0] + bv.x, acc[r][1] + bv.y);
    }
  }
}

// ---------------- layer-1 aggregation + LeakyReLU + L2 normalize ----------------
// one wave per destination row; lane covers 2 of 128 cols. Per-row weights are
// 3 wave-uniform scalar loads; per-edge rel selects among them (no ew array).

__global__ __launch_bounds__(256) void k_agg_norm(const float* __restrict__ support,
                                                  const int* __restrict__ row_ptr,
                                                  const unsigned* __restrict__ esrc,
                                                  const float* __restrict__ inv1,
                                                  float* __restrict__ out, int N) {
  int wv = blockIdx.x * 4 + (threadIdx.x >> 6);
  if (wv >= N) return;
  int row = __builtin_amdgcn_readfirstlane(wv);
  int lane2 = (threadIdx.x & 63) * 2;
  int s = row_ptr[row], e = row_ptr[row + 1];
  float w0 = inv1[row], w1 = inv1[N + row], w2 = inv1[2 * N + row];
  float ax = 0.f, ay = 0.f;
  for (int j = s; j < e; ++j) {
    unsigned u = esrc[j];
    int rel = (int)(u >> 16);
    int src = (int)(u & 0xFFFFu);
    float w = (rel == 0) ? w0 : ((rel == 1) ? w1 : w2);
    float2 v = *(const float2*)&support[(size_t)src * 128 + lane2];
    ax += w * v.x;
    ay += w * v.y;
  }
  ax = ax > 0.f ? ax : LEAKY_SLOPE * ax;
  ay = ay > 0.f ? ay : LEAKY_SLOPE * ay;
  float ss = ax * ax + ay * ay;
#pragma unroll
  for (int m = 1; m < 64; m <<= 1) ss += __shfl_xor(ss, m, 64);
  float inv = 1.0f / fmaxf(sqrtf(ss), 1e-12f);
  *(float2*)&out[(size_t)row * 128 + lane2] = make_float2(ax * inv, ay * inv);
}

// ---------------- layer-2: zero labeled rows, atomic hit aggregation, final ----------------

__global__ __launch_bounds__(256) void k_zero_rows(const int* __restrict__ lidx,
                                                   float* __restrict__ buf, int L) {
  int wv = blockIdx.x * 4 + (threadIdx.x >> 6);
  if (wv >= L) return;
  int row = lidx[wv];
  int lane2 = (threadIdx.x & 63) * 2;
  *(float2*)&buf[(size_t)row * 128 + lane2] = make_float2(0.f, 0.f);
}

__global__ __launch_bounds__(256) void k_hit_agg(const float* __restrict__ support,
                                                 const int* __restrict__ hsrc,
                                                 const int* __restrict__ hpack,
                                                 const int* __restrict__ deg2,
                                                 const float* __restrict__ a_soft,
                                                 const int* __restrict__ counter,
                                                 float* __restrict__ out, int N) {
  int lane2 = (threadIdx.x & 63) * 2;
  int wv = blockIdx.x * 4 + (threadIdx.x >> 6);
  int nw = gridDim.x * 4;
  int cnt = counter[0];
  for (int i = wv; i < cnt; i += nw) {
    int src = hsrc[i], pk = hpack[i];
    int rel = pk >> 20, d = pk & 0xFFFFF;
    float w = a_soft[3 + rel] / (float)deg2[rel * N + d];
    float2 v = *(const float2*)&support[(size_t)src * 128 + lane2];
    atomicAdd(&out[(size_t)d * 128 + lane2], w * v.x);
    atomicAdd(&out[(size_t)d * 128 + lane2 + 1], w * v.y);
  }
}

__global__ __launch_bounds__(256) void k_final(const float* __restrict__ buf,
                                               const int* __restrict__ lidx,
                                               float* __restrict__ out, int L) {
  int wv = blockIdx.x * 4 + (threadIdx.x >> 6);
  if (wv >= L) return;
  int row = lidx[wv];
  int lane2 = (threadIdx.x & 63) * 2;
  float2 v = *(const float2*)&buf[(size_t)row * 128 + lane2];
  float ax = v.x > 0.f ? v.x : LEAKY_SLOPE * v.x;
  float ay = v.y > 0.f ? v.y : LEAKY_SLOPE * v.y;
  float ss = ax * ax + ay * ay;
#pragma unroll
  for (int m = 1; m < 64; m <<= 1) ss += __shfl_xor(ss, m, 64);
  float inv = 1.0f / fmaxf(sqrtf(ss), 1e-12f);
  *(float2*)&out[(size_t)wv * 128 + lane2] = make_float2(ax * inv, ay * inv);
}

// ---------------- host ----------------

extern "C" void kernel_launch(void* const* d_in, const int* in_sizes, int n_in,
                              void* d_out, int out_size, void* d_ws, size_t ws_size,
                              hipStream_t stream) {
  const float* feat  = (const float*)d_in[0];
  const float* w1    = (const float*)d_in[1];
  const float* b1    = (const float*)d_in[2];
  const float* w2    = (const float*)d_in[3];
  const float* b2    = (const float*)d_in[4];
  const float* a_att = (const float*)d_in[5];
  const float* r_att = (const float*)d_in[6];
  const int* rows    = (const int*)d_in[7];
  const int* cols    = (const int*)d_in[8];
  const int* lidx    = (const int*)d_in[9];

  const int F = 128;
  int K1 = in_sizes[1] / F;        // 300
  int N  = in_sizes[0] / K1;       // 50000
  int E  = in_sizes[7] / 3;        // 800000
  int L  = in_sizes[9];            // 1000
  float* outp = (float*)d_out;
  (void)n_in; (void)out_size; (void)ws_size;

  int WN = (N + 1) >> 1;
  int chunk = (E + HIST_C - 1) / HIST_C;

  char* base = (char*)d_ws;
  size_t off = 0;
  auto take = [&](size_t bytes) -> void* {
    size_t cur = (off + 255) & ~(size_t)255;
    off = cur + bytes;
    return (void*)(base + cur);
  };
  float* bufA  = (float*)take((size_t)N * F * 4);          // support1 / support2
  float* bufB  = (float*)take((size_t)N * F * 4);          // h1 / out2-accum
  unsigned* esrc = (unsigned*)take((size_t)3 * E * 4);
  unsigned short* rank16 = (unsigned short*)take((size_t)3 * E * 2);
  unsigned* histw = (unsigned*)take((size_t)3 * HIST_C * WN * 4);
  float* inv1  = (float*)take((size_t)3 * N * 4);
  int* rowdeg  = (int*)take((size_t)N * 4);
  int* row_ptr = (int*)take((size_t)(N + 1) * 4);
  int*   hsrc  = (int*)take((size_t)1000000 * 4);
  int*   hpack = (int*)take((size_t)1000000 * 4);
  int nb = (N + 31) / 32;
  int zn = 3 * N + nb + 1;                                 // deg2 + bitmap + counter
  int* deg2 = (int*)take((size_t)zn * 4);
  unsigned* bm = (unsigned*)(deg2 + 3 * N);
  int* counter = (int*)(bm + nb);
  float* a_soft = (float*)take(64);
  int* chunk_sums = (int*)take(256);
  int* chunk_offs = (int*)take(256);

  int nchunks = (N + 1023) / 1024;
  size_t shbytes = (size_t)WN * 4 + (size_t)HIST_THREADS * 8 + 16;
  hipFuncSetAttribute((const void*)k_hist, hipFuncAttributeMaxDynamicSharedMemorySize,
                      (int)shbytes);

  hipLaunchKernelGGL(k_zero, dim3((zn + 255) / 256), dim3(256), 0, stream, deg2, zn);
  hipLaunchKernelGGL(k_softmax3, dim3(1), dim3(64), 0, stream, a_att, r_att, a_soft);
  hipLaunchKernelGGL(k_bitmap, dim3((L + 255) / 256), dim3(256), 0, stream, lidx, bm, L);
  hipLaunchKernelGGL(k_hist, dim3(HIST_C, 3), dim3(HIST_THREADS), shbytes, stream,
                     rows, cols, bm, deg2, counter, hsrc, hpack, rank16, histw, N, E, chunk);
  hipLaunchKernelGGL(k_gemm_bias, dim3((N + 31) / 32), dim3(256), 0, stream,
                     feat, w1, b1, bufA, N, K1);
  hipLaunchKernelGGL(k_reduce, dim3((WN + 255) / 256), dim3(256), 0, stream,
                     histw, a_soft, inv1, rowdeg, N);
  hipLaunchKernelGGL(k_scan1, dim3(nchunks), dim3(256), 0, stream, rowdeg, row_ptr, chunk_sums, N);
  hipLaunchKernelGGL(k_scan2, dim3(1), dim3(64), 0, stream, chunk_sums, chunk_offs, nchunks, row_ptr, N);
  hipLaunchKernelGGL(k_scan3, dim3((N + 255) / 256), dim3(256), 0, stream, row_ptr, chunk_offs, N);
  hipLaunchKernelGGL(k_scatter, dim3((E + 255) / 256, 3), dim3(256), 0, stream,
                     rows, cols, row_ptr, histw, rank16, esrc, N, E, chunk);
  hipLaunchKernelGGL(k_agg_norm, dim3((N + 3) / 4), dim3(256), 0, stream,
                     bufA, row_ptr, esrc, inv1, bufB, N);
  hipLaunchKernelGGL(k_gemm_bias, dim3((N + 31) / 32), dim3(256), 0, stream,
                     bufB, w2, b2, bufA, N, F);
  hipLaunchKernelGGL(k_zero_rows, dim3((L + 3) / 4), dim3(256), 0, stream, lidx, bufB, L);
  hipLaunchKernelGGL(k_hit_agg, dim3(512), dim3(256), 0, stream,
                     bufA, hsrc, hpack, deg2, a_soft, counter, bufB, N);
  hipLaunchKernelGGL(k_final, dim3((L + 3) / 4), dim3(256), 0, stream, bufB, lidx, outp, L);
}

// Round 4
// 406.596 us; speedup vs baseline: 4.2024x; 1.3723x over previous
//
#include <hip/hip_runtime.h>
#include <hip/hip_bf16.h>

#define LEAKY_SLOPE 0.2f
#define HIST_C 85          // chunks per relation for privatized histogram
#define HIST_THREADS 1024

// ---------------- utility kernels ----------------

__global__ __launch_bounds__(256) void k_zero(int* __restrict__ p, int n, int val) {
  int i = blockIdx.x * 256 + threadIdx.x;
  if (i < n) p[i] = val;
}

__global__ __launch_bounds__(64) void k_softmax3(const float* __restrict__ a_att,
                                                 const float* __restrict__ r_att,
                                                 float* __restrict__ a_soft) {
  if (threadIdx.x == 0) {
    float m = fmaxf(fmaxf(a_att[0], a_att[1]), a_att[2]);
    float e0 = expf(a_att[0] - m), e1 = expf(a_att[1] - m), e2 = expf(a_att[2] - m);
    float s = 1.0f / (e0 + e1 + e2);
    a_soft[0] = e0 * s; a_soft[1] = e1 * s; a_soft[2] = e2 * s;
    m = fmaxf(fmaxf(r_att[0], r_att[1]), r_att[2]);
    e0 = expf(r_att[0] - m); e1 = expf(r_att[1] - m); e2 = expf(r_att[2] - m);
    s = 1.0f / (e0 + e1 + e2);
    a_soft[3] = e0 * s; a_soft[4] = e1 * s; a_soft[5] = e2 * s;
  }
}

// label bitmap + canonical slot map (deterministic via atomicMax; handles dup labels)
__global__ __launch_bounds__(256) void k_lab(const int* __restrict__ lidx,
                                             unsigned* __restrict__ bm,
                                             int* __restrict__ lab_of, int L) {
  int i = blockIdx.x * 256 + threadIdx.x;
  if (i < L) {
    int n = lidx[i];
    atomicOr(&bm[n >> 5], 1u << (n & 31));
    atomicMax(&lab_of[n], i);
  }
}

// ---------------- LDS-privatized histogram + rank assignment ----------------
// grid (HIST_C, 3). Packed-u16 LDS histogram; LDS atomic return = local rank.
// Also: layer-2 hit detection (deg2, block-aggregated hit list) and flagging of
// hit-edge SOURCES (the only rows whose h1 is ever needed).
__global__ __launch_bounds__(HIST_THREADS) void k_hist(const int* __restrict__ rows,
                                                       const int* __restrict__ cols,
                                                       const unsigned* __restrict__ bm,
                                                       int* __restrict__ deg2,
                                                       unsigned* __restrict__ flag_bm,
                                                       int* __restrict__ counter,
                                                       int* __restrict__ hsrc, int* __restrict__ hpack,
                                                       unsigned short* __restrict__ rank16,
                                                       unsigned* __restrict__ histw,
                                                       int N, int E, int chunk) {
  extern __shared__ unsigned sh[];
  int WN = (N + 1) >> 1;
  unsigned* hist = sh;                       // WN words (packed u16 pair)
  int* s_src = (int*)(sh + WN);              // [HIST_THREADS]
  int* s_pack = s_src + HIST_THREADS;        // [HIST_THREADS]
  int* s_meta = s_pack + HIST_THREADS;       // [0]=cnt [1]=base
  int tid = threadIdx.x;
  int cidx = blockIdx.x, rel = blockIdx.y;

  for (int i = tid; i < WN; i += HIST_THREADS) hist[i] = 0;
  __syncthreads();

  int estart = cidx * chunk;
  int eend = min(estart + chunk, E);
  for (int eb = estart; eb < eend; eb += HIST_THREADS) {
    if (tid == 0) s_meta[0] = 0;
    __syncthreads();
    int e = eb + tid;
    if (e < eend) {
      int r = rows[rel * E + e];   // layer-1 dest / layer-2 src
      int c = cols[rel * E + e];   // layer-1 src / layer-2 dest
      unsigned old = atomicAdd(&hist[r >> 1], 1u << (16 * (r & 1)));
      rank16[rel * E + e] = (unsigned short)((old >> (16 * (r & 1))) & 0xFFFFu);
      if ((bm[c >> 5] >> (c & 31)) & 1u) {
        atomicAdd(&deg2[rel * N + c], 1);
        atomicOr(&flag_bm[r >> 5], 1u << (r & 31));   // h1[r] will be needed
        int p = atomicAdd(&s_meta[0], 1);
        s_src[p] = r;
        s_pack[p] = (rel << 20) | c;         // N < 2^20
      }
    }
    __syncthreads();
    int cnt = s_meta[0];
    if (tid == 0 && cnt > 0) s_meta[1] = atomicAdd(counter, cnt);
    __syncthreads();
    if (tid < cnt) {
      int b = s_meta[1];
      hsrc[b + tid] = s_src[tid];
      hpack[b + tid] = s_pack[tid];
    }
    __syncthreads();
  }
  unsigned* dst = &histw[(size_t)(rel * HIST_C + cidx) * WN];
  for (int i = tid; i < WN; i += HIST_THREADS) dst[i] = hist[i];
}

// ---------------- reduce copies -> in-place absolute bases + inv-weights ----------------
__global__ __launch_bounds__(256) void k_reduce(unsigned* __restrict__ histw,
                                                const float* __restrict__ a_soft,
                                                float* __restrict__ inv1,
                                                int* __restrict__ rowdeg, int N) {
  int WN = (N + 1) >> 1;
  int t = blockIdx.x * 256 + threadIdx.x;
  if (t >= WN) return;
  int d0 = 2 * t, d1 = 2 * t + 1;
  int tot0 = 0, tot1 = 0;
#pragma unroll
  for (int rel = 0; rel < 3; ++rel) {
    int run0 = tot0, run1 = tot1;
    for (int c = 0; c < HIST_C; ++c) {
      size_t idx = (size_t)(rel * HIST_C + c) * WN + t;
      unsigned w = histw[idx];
      histw[idx] = (unsigned)(run0 & 0xFFFF) | ((unsigned)(run1 & 0xFFFF) << 16);
      run0 += (int)(w & 0xFFFFu);
      run1 += (int)(w >> 16);
    }
    int dg0 = run0 - tot0, dg1 = run1 - tot1;
    float a = a_soft[rel];
    inv1[rel * N + d0] = a / (float)max(dg0, 1);
    if (d1 < N) inv1[rel * N + d1] = a / (float)max(dg1, 1);
    tot0 = run0; tot1 = run1;
  }
  rowdeg[d0] = tot0;
  if (d1 < N) rowdeg[d1] = tot1;
}

// ---------------- prefix sum over rowdeg ----------------

__global__ __launch_bounds__(256) void k_scan1(const int* __restrict__ rowdeg,
                                               int* __restrict__ row_ptr,
                                               int* __restrict__ chunk_sums, int N) {
  __shared__ int sd[256];
  int tid = threadIdx.x;
  int n0 = blockIdx.x * 1024 + tid * 4;
  int v[4];
#pragma unroll
  for (int i = 0; i < 4; ++i) {
    int n = n0 + i;
    v[i] = (n < N) ? rowdeg[n] : 0;
  }
  sd[tid] = v[0] + v[1] + v[2] + v[3];
  __syncthreads();
  for (int off = 1; off < 256; off <<= 1) {
    int t = (tid >= off) ? sd[tid - off] : 0;
    __syncthreads();
    sd[tid] += t;
    __syncthreads();
  }
  int run = tid ? sd[tid - 1] : 0;
#pragma unroll
  for (int i = 0; i < 4; ++i) {
    int n = n0 + i;
    if (n < N) row_ptr[n] = run;
    run += v[i];
  }
  if (tid == 255) chunk_sums[blockIdx.x] = sd[255];
}

__global__ __launch_bounds__(64) void k_scan2(const int* __restrict__ chunk_sums,
                                              int* __restrict__ chunk_offs,
                                              int nchunks, int* __restrict__ row_ptr, int N) {
  int lane = threadIdx.x;
  int mine = (lane < nchunks) ? chunk_sums[lane] : 0;
  int v = mine;
  for (int off = 1; off < 64; off <<= 1) {
    int t = __shfl_up(v, off, 64);
    if (lane >= off) v += t;
  }
  if (lane < nchunks) chunk_offs[lane] = v - mine;
  int total = __shfl(v, nchunks - 1, 64);
  if (lane == 0) row_ptr[N] = total;
}

__global__ __launch_bounds__(256) void k_scan3(int* __restrict__ row_ptr,
                                               const int* __restrict__ chunk_offs, int N) {
  int n = blockIdx.x * 256 + threadIdx.x;
  if (n < N) row_ptr[n] += chunk_offs[n >> 10];
}

// ---------------- atomic-free scatter (only for flagged dests) ----------------

__global__ __launch_bounds__(256) void k_scatter(const int* __restrict__ rows,
                                                 const int* __restrict__ cols,
                                                 const int* __restrict__ row_ptr,
                                                 const unsigned* __restrict__ histw,
                                                 const unsigned short* __restrict__ rank16,
                                                 const unsigned* __restrict__ flag_bm,
                                                 unsigned* __restrict__ esrc,
                                                 int N, int E, int chunk) {
  int e = blockIdx.x * 256 + threadIdx.x;
  int rel = blockIdx.y;
  if (e >= E) return;
  int d = rows[rel * E + e];
  if (!((flag_bm[d >> 5] >> (d & 31)) & 1u)) return;   // h1[d] never consumed
  int s = cols[rel * E + e];
  int WN = (N + 1) >> 1;
  int c = e / chunk;
  const unsigned short* cb = (const unsigned short*)histw;
  int pos = row_ptr[d] + (int)cb[(size_t)(rel * HIST_C + c) * (2 * WN) + d]
          + (int)rank16[rel * E + e];
  esrc[pos] = ((unsigned)rel << 16) | (unsigned)s;   // src < 2^16
}

// ---------------- GEMM1: supp_bf[M][128] = bf16(A[M][K] @ W[K][128] + bias) ----------------

__global__ __launch_bounds__(256) void k_gemm1(const float* __restrict__ A,
                                               const float* __restrict__ W,
                                               const float* __restrict__ bias,
                                               unsigned short* __restrict__ outbf,
                                               int M, int K) {
  __shared__ float sW[64][128];   // 32 KB
  __shared__ float sA[32][64];    // 8 KB
  int tid = threadIdx.x;
  int wave = tid >> 6, lane = tid & 63;
  int lane2 = lane * 2;
  int row0 = blockIdx.x * 32;
  float acc[8][2] = {};
  for (int k0 = 0; k0 < K; k0 += 64) {
    int kc = min(64, K - k0);
    __syncthreads();
    for (int i = tid; i < kc * 32; i += 256) {
      int kk = i >> 5, c4 = i & 31;
      ((float4*)&sW[kk][0])[c4] = ((const float4*)&W[(size_t)(k0 + kk) * 128])[c4];
    }
    int kq4 = kc >> 2;
    for (int i = tid; i < 32 * kq4; i += 256) {
      int r = i / kq4, kq = i - r * kq4;
      int gr = row0 + r;
      float4 v = make_float4(0.f, 0.f, 0.f, 0.f);
      if (gr < M) v = ((const float4*)&A[(size_t)gr * K + k0])[kq];
      ((float4*)&sA[r][0])[kq] = v;
    }
    __syncthreads();
    const float* ap = &sA[wave * 8][0];
    for (int kk = 0; kk < kc; kk += 2) {
      float2 w0 = *(const float2*)&sW[kk][lane2];
      float2 w1 = *(const float2*)&sW[kk + 1][lane2];
#pragma unroll
      for (int r = 0; r < 8; ++r) {
        float2 av = *(const float2*)&ap[r * 64 + kk];
        acc[r][0] += av.x * w0.x + av.y * w1.x;
        acc[r][1] += av.x * w0.y + av.y * w1.y;
      }
    }
  }
  float2 bv = *(const float2*)&bias[lane2];
#pragma unroll
  for (int r = 0; r < 8; ++r) {
    int gr = row0 + wave * 8 + r;
    if (gr < M) {
      __hip_bfloat16 h0 = __float2bfloat16(acc[r][0] + bv.x);
      __hip_bfloat16 h1 = __float2bfloat16(acc[r][1] + bv.y);
      unsigned pk = (unsigned)(*(unsigned short*)&h0) |
                    ((unsigned)(*(unsigned short*)&h1) << 16);
      ((unsigned*)&outbf[(size_t)gr * 128])[lane] = pk;
    }
  }
}

// ---------------- layer-1 aggregation + LeakyReLU + L2 norm (flagged rows only) ----------------

__global__ __launch_bounds__(256) void k_agg_norm(const unsigned short* __restrict__ supp,
                                                  const int* __restrict__ row_ptr,
                                                  const unsigned* __restrict__ esrc,
                                                  const float* __restrict__ inv1,
                                                  const unsigned* __restrict__ flag_bm,
                                                  float* __restrict__ out, int N) {
  int wv = blockIdx.x * 4 + (threadIdx.x >> 6);
  if (wv >= N) return;
  int row = __builtin_amdgcn_readfirstlane(wv);
  if (!((flag_bm[row >> 5] >> (row & 31)) & 1u)) return;   // never consumed
  int lane = threadIdx.x & 63;
  int s = row_ptr[row], e = row_ptr[row + 1];
  float w0 = inv1[row], w1 = inv1[N + row], w2 = inv1[2 * N + row];
  float ax = 0.f, ay = 0.f;
  for (int j = s; j < e; ++j) {
    unsigned u = esrc[j];
    int rel = (int)(u >> 16);
    int src = (int)(u & 0xFFFFu);
    float w = (rel == 0) ? w0 : ((rel == 1) ? w1 : w2);
    unsigned pv = ((const unsigned*)&supp[(size_t)src * 128])[lane];
    float vx = __uint_as_float(pv << 16);
    float vy = __uint_as_float(pv & 0xFFFF0000u);
    ax += w * vx;
    ay += w * vy;
  }
  ax = ax > 0.f ? ax : LEAKY_SLOPE * ax;
  ay = ay > 0.f ? ay : LEAKY_SLOPE * ay;
  float ss = ax * ax + ay * ay;
#pragma unroll
  for (int m = 1; m < 64; m <<= 1) ss += __shfl_xor(ss, m, 64);
  float inv = 1.0f / fmaxf(sqrtf(ss), 1e-12f);
  *(float2*)&out[(size_t)row * 128 + lane * 2] = make_float2(ax * inv, ay * inv);
}

// ---------------- layer-2 small path ----------------
// counts + exclusive scan over label slots (single block; L <= 1024)
__global__ __launch_bounds__(1024) void k_cnt2(const int* __restrict__ lidx,
                                               const int* __restrict__ lab_of,
                                               const int* __restrict__ deg2,
                                               const float* __restrict__ a_soft,
                                               int* __restrict__ hb_ptr,
                                               int* __restrict__ cnt2,
                                               int* __restrict__ fill2,
                                               float* __restrict__ sumw, int N, int L) {
  __shared__ int sd[1024];
  int t = threadIdx.x;
  int cnt = 0;
  if (t < L) {
    int d = lidx[t];
    int c0 = deg2[d], c1 = deg2[N + d], c2 = deg2[2 * N + d];
    if (lab_of[d] == t) cnt = c0 + c1 + c2;       // canonical slot owns the edges
    sumw[t] = a_soft[3] * (c0 > 0 ? 1.f : 0.f) +
              a_soft[4] * (c1 > 0 ? 1.f : 0.f) +
              a_soft[5] * (c2 > 0 ? 1.f : 0.f);
  }
  sd[t] = cnt;
  __syncthreads();
  for (int off = 1; off < 1024; off <<= 1) {
    int v = (t >= off) ? sd[t - off] : 0;
    __syncthreads();
    sd[t] += v;
    __syncthreads();
  }
  if (t < L) {
    int base = sd[t] - cnt;
    hb_ptr[t] = base;
    fill2[t] = base;
    cnt2[t] = cnt;
  }
}

// scatter hit edges into per-label CSR (spread atomics over <=1000 counters)
__global__ __launch_bounds__(256) void k_scatter2(const int* __restrict__ hsrc,
                                                  const int* __restrict__ hpack,
                                                  const int* __restrict__ counter,
                                                  const int* __restrict__ lab_of,
                                                  int* __restrict__ fill2,
                                                  unsigned* __restrict__ hdata) {
  int cnt = counter[0];
  for (int i = blockIdx.x * 256 + threadIdx.x; i < cnt; i += gridDim.x * 256) {
    int src = hsrc[i], pk = hpack[i];
    int rel = pk >> 20, d = pk & 0xFFFFF;
    int li = lab_of[d];
    int pos = atomicAdd(&fill2[li], 1);
    hdata[pos] = ((unsigned)rel << 16) | (unsigned)src;
  }
}

// aggregate h1 rows per canonical label slot: aggh[li] = sum w * h1[src]
__global__ __launch_bounds__(256) void k_agg2(const float* __restrict__ h1,
                                              const int* __restrict__ hb_ptr,
                                              const int* __restrict__ cnt2,
                                              const unsigned* __restrict__ hdata,
                                              const int* __restrict__ lidx,
                                              const int* __restrict__ deg2,
                                              const float* __restrict__ a_soft,
                                              float* __restrict__ aggh, int N, int L) {
  int wv = blockIdx.x * 4 + (threadIdx.x >> 6);
  if (wv >= L) return;
  int li = __builtin_amdgcn_readfirstlane(wv);
  int lane2 = (threadIdx.x & 63) * 2;
  int d = lidx[li];
  int s = hb_ptr[li], cnt = cnt2[li];
  float w0 = a_soft[3] / (float)max(deg2[d], 1);
  float w1 = a_soft[4] / (float)max(deg2[N + d], 1);
  float w2 = a_soft[5] / (float)max(deg2[2 * N + d], 1);
  float ax = 0.f, ay = 0.f;
  for (int j = s; j < s + cnt; ++j) {
    unsigned u = hdata[j];
    int rel = (int)(u >> 16);
    int src = (int)(u & 0xFFFFu);
    float w = (rel == 0) ? w0 : ((rel == 1) ? w1 : w2);
    float2 v = *(const float2*)&h1[(size_t)src * 128 + lane2];
    ax += w * v.x;
    ay += w * v.y;
  }
  *(float2*)&aggh[(size_t)li * 128 + lane2] = make_float2(ax, ay);
}

// final: out[li] = normalize(leaky(aggh[canon(li)] @ W2 + b2*sumw[li]))
__global__ __launch_bounds__(256) void k_final(const float* __restrict__ aggh,
                                               const float* __restrict__ W2,
                                               const float* __restrict__ b2,
                                               const float* __restrict__ sumw,
                                               const int* __restrict__ lidx,
                                               const int* __restrict__ lab_of,
                                               float* __restrict__ out, int L) {
  __shared__ float sW[64][128];   // 32 KB
  __shared__ float sA[32][64];    // 8 KB
  __shared__ int s_c[32];
  __shared__ float s_sw[32];
  int tid = threadIdx.x;
  int wave = tid >> 6, lane = tid & 63;
  int lane2 = lane * 2;
  int row0 = blockIdx.x * 32;
  if (tid < 32) {
    int gr = row0 + tid;
    int c = 0; float sw = 0.f;
    if (gr < L) { c = lab_of[lidx[gr]]; sw = sumw[gr]; }
    s_c[tid] = c; s_sw[tid] = sw;
  }
  __syncthreads();
  float acc[8][2] = {};
  for (int k0 = 0; k0 < 128; k0 += 64) {
    __syncthreads();
    for (int i = tid; i < 64 * 32; i += 256) {
      int kk = i >> 5, c4 = i & 31;
      ((float4*)&sW[kk][0])[c4] = ((const float4*)&W2[(size_t)(k0 + kk) * 128])[c4];
    }
    for (int i = tid; i < 32 * 16; i += 256) {
      int r = i >> 4, kq = i & 15;
      int gr = row0 + r;
      float4 v = make_float4(0.f, 0.f, 0.f, 0.f);
      if (gr < L) v = ((const float4*)&aggh[(size_t)s_c[r] * 128 + k0])[kq];
      ((float4*)&sA[r][0])[kq] = v;
    }
    __syncthreads();
    const float* ap = &sA[wave * 8][0];
    for (int kk = 0; kk < 64; kk += 2) {
      float2 w0 = *(const float2*)&sW[kk][lane2];
      float2 w1 = *(const float2*)&sW[kk + 1][lane2];
#pragma unroll
      for (int r = 0; r < 8; ++r) {
        float2 av = *(const float2*)&ap[r * 64 + kk];
        acc[r][0] += av.x * w0.x + av.y * w1.x;
        acc[r][1] += av.x * w0.y + av.y * w1.y;
      }
    }
  }
  float2 bv = *(const float2*)&b2[lane2];
#pragma unroll
  for (int r = 0; r < 8; ++r) {
    int gr = row0 + wave * 8 + r;
    float sw = s_sw[wave * 8 + r];
    float ax = acc[r][0] + bv.x * sw;
    float ay = acc[r][1] + bv.y * sw;
    ax = ax > 0.f ? ax : LEAKY_SLOPE * ax;
    ay = ay > 0.f ? ay : LEAKY_SLOPE * ay;
    float ss = ax * ax + ay * ay;
#pragma unroll
    for (int m = 1; m < 64; m <<= 1) ss += __shfl_xor(ss, m, 64);
    float inv = 1.0f / fmaxf(sqrtf(ss), 1e-12f);
    if (gr < L) {
      *(float2*)&out[(size_t)gr * 128 + lane2] = make_float2(ax * inv, ay * inv);
    }
  }
}

// ---------------- host ----------------

extern "C" void kernel_launch(void* const* d_in, const int* in_sizes, int n_in,
                              void* d_out, int out_size, void* d_ws, size_t ws_size,
                              hipStream_t stream) {
  const float* feat  = (const float*)d_in[0];
  const float* w1    = (const float*)d_in[1];
  const float* b1    = (const float*)d_in[2];
  const float* w2    = (const float*)d_in[3];
  const float* b2    = (const float*)d_in[4];
  const float* a_att = (const float*)d_in[5];
  const float* r_att = (const float*)d_in[6];
  const int* rows    = (const int*)d_in[7];
  const int* cols    = (const int*)d_in[8];
  const int* lidx    = (const int*)d_in[9];

  const int F = 128;
  int K1 = in_sizes[1] / F;        // 300
  int N  = in_sizes[0] / K1;       // 50000
  int E  = in_sizes[7] / 3;        // 800000
  int L  = in_sizes[9];            // 1000
  float* outp = (float*)d_out;
  (void)n_in; (void)out_size; (void)ws_size;

  int WN = (N + 1) >> 1;
  int chunk = (E + HIST_C - 1) / HIST_C;

  char* base = (char*)d_ws;
  size_t off = 0;
  auto take = [&](size_t bytes) -> void* {
    size_t cur = (off + 255) & ~(size_t)255;
    off = cur + bytes;
    return (void*)(base + cur);
  };
  unsigned short* suppbf = (unsigned short*)take((size_t)N * F * 2);
  float* h1    = (float*)take((size_t)N * F * 4);
  unsigned* esrc = (unsigned*)take((size_t)3 * E * 4);
  unsigned short* rank16 = (unsigned short*)take((size_t)3 * E * 2);
  unsigned* histw = (unsigned*)take((size_t)3 * HIST_C * WN * 4);
  float* inv1  = (float*)take((size_t)3 * N * 4);
  int* rowdeg  = (int*)take((size_t)N * 4);
  int* row_ptr = (int*)take((size_t)(N + 1) * 4);
  int* hsrc  = (int*)take((size_t)1000000 * 4);
  int* hpack = (int*)take((size_t)1000000 * 4);
  unsigned* hdata = (unsigned*)take((size_t)1000000 * 4);
  float* aggh = (float*)take((size_t)1024 * F * 4);
  int* lab_of = (int*)take((size_t)N * 4);
  int nb = (N + 31) / 32;
  int zn = 3 * N + 2 * nb + 1;                  // deg2 + bm + flag_bm + counter
  int* deg2 = (int*)take((size_t)zn * 4);
  unsigned* bm = (unsigned*)(deg2 + 3 * N);
  unsigned* flag_bm = bm + nb;
  int* counter = (int*)(flag_bm + nb);
  int* hb_ptr = (int*)take(1024 * 4);
  int* cnt2   = (int*)take(1024 * 4);
  int* fill2  = (int*)take(1024 * 4);
  float* sumw = (float*)take(1024 * 4);
  float* a_soft = (float*)take(64);
  int* chunk_sums = (int*)take(256);
  int* chunk_offs = (int*)take(256);

  int nchunks = (N + 1023) / 1024;
  size_t shbytes = (size_t)WN * 4 + (size_t)HIST_THREADS * 8 + 16;
  hipFuncSetAttribute((const void*)k_hist, hipFuncAttributeMaxDynamicSharedMemorySize,
                      (int)shbytes);

  hipLaunchKernelGGL(k_zero, dim3((zn + 255) / 256), dim3(256), 0, stream, deg2, zn, 0);
  hipLaunchKernelGGL(k_zero, dim3((N + 255) / 256), dim3(256), 0, stream, lab_of, N, -1);
  hipLaunchKernelGGL(k_softmax3, dim3(1), dim3(64), 0, stream, a_att, r_att, a_soft);
  hipLaunchKernelGGL(k_lab, dim3((L + 255) / 256), dim3(256), 0, stream, lidx, bm, lab_of, L);
  hipLaunchKernelGGL(k_hist, dim3(HIST_C, 3), dim3(HIST_THREADS), shbytes, stream,
                     rows, cols, bm, deg2, flag_bm, counter, hsrc, hpack, rank16, histw,
                     N, E, chunk);
  hipLaunchKernelGGL(k_gemm1, dim3((N + 31) / 32), dim3(256), 0, stream,
                     feat, w1, b1, suppbf, N, K1);
  hipLaunchKernelGGL(k_reduce, dim3((WN + 255) / 256), dim3(256), 0, stream,
                     histw, a_soft, inv1, rowdeg, N);
  hipLaunchKernelGGL(k_scan1, dim3(nchunks), dim3(256), 0, stream, rowdeg, row_ptr, chunk_sums, N);
  hipLaunchKernelGGL(k_scan2, dim3(1), dim3(64), 0, stream, chunk_sums, chunk_offs, nchunks, row_ptr, N);
  hipLaunchKernelGGL(k_scan3, dim3((N + 255) / 256), dim3(256), 0, stream, row_ptr, chunk_offs, N);
  hipLaunchKernelGGL(k_scatter, dim3((E + 255) / 256, 3), dim3(256), 0, stream,
                     rows, cols, row_ptr, histw, rank16, flag_bm, esrc, N, E, chunk);
  hipLaunchKernelGGL(k_agg_norm, dim3((N + 3) / 4), dim3(256), 0, stream,
                     suppbf, row_ptr, esrc, inv1, flag_bm, h1, N);
  hipLaunchKernelGGL(k_cnt2, dim3(1), dim3(1024), 0, stream,
                     lidx, lab_of, deg2, a_soft, hb_ptr, cnt2, fill2, sumw, N, L);
  hipLaunchKernelGGL(k_scatter2, dim3(256), dim3(256), 0, stream,
                     hsrc, hpack, counter, lab_of, fill2, hdata);
  hipLaunchKernelGGL(k_agg2, dim3((L + 3) / 4), dim3(256), 0, stream,
                     h1, hb_ptr, cnt2, hdata, lidx, deg2, a_soft, aggh, N, L);
  hipLaunchKernelGGL(k_final, dim3((L + 31) / 32), dim3(256), 0, stream,
                     aggh, w2, b2, sumw, lidx, lab_of, outp, L);
}

// Round 5
// 404.879 us; speedup vs baseline: 4.2202x; 1.0042x over previous
//
#include <hip/hip_runtime.h>
#include <hip/hip_bf16.h>

#define LEAKY_SLOPE 0.2f
#define HIST_C 85          // chunks per relation for privatized histogram
#define HIST_THREADS 1024

// ---------------- utility kernels ----------------

__global__ __launch_bounds__(256) void k_zero(int* __restrict__ p, int n, int val) {
  int i = blockIdx.x * 256 + threadIdx.x;
  if (i < n) p[i] = val;
}

__global__ __launch_bounds__(64) void k_softmax3(const float* __restrict__ a_att,
                                                 const float* __restrict__ r_att,
                                                 float* __restrict__ a_soft) {
  if (threadIdx.x == 0) {
    float m = fmaxf(fmaxf(a_att[0], a_att[1]), a_att[2]);
    float e0 = expf(a_att[0] - m), e1 = expf(a_att[1] - m), e2 = expf(a_att[2] - m);
    float s = 1.0f / (e0 + e1 + e2);
    a_soft[0] = e0 * s; a_soft[1] = e1 * s; a_soft[2] = e2 * s;
    m = fmaxf(fmaxf(r_att[0], r_att[1]), r_att[2]);
    e0 = expf(r_att[0] - m); e1 = expf(r_att[1] - m); e2 = expf(r_att[2] - m);
    s = 1.0f / (e0 + e1 + e2);
    a_soft[3] = e0 * s; a_soft[4] = e1 * s; a_soft[5] = e2 * s;
  }
}

// label bitmap + canonical slot map (deterministic via atomicMax; handles dup labels)
__global__ __launch_bounds__(256) void k_lab(const int* __restrict__ lidx,
                                             unsigned* __restrict__ bm,
                                             int* __restrict__ lab_of, int L) {
  int i = blockIdx.x * 256 + threadIdx.x;
  if (i < L) {
    int n = lidx[i];
    atomicOr(&bm[n >> 5], 1u << (n & 31));
    atomicMax(&lab_of[n], i);
  }
}

// ---------------- LDS-privatized histogram + rank assignment ----------------
// grid (HIST_C, 3). Packed-u16 LDS histogram; LDS atomic return = local rank.
// Also: layer-2 hit detection (deg2, block-aggregated hit list) and flagging of
// hit-edge SOURCES (the only rows whose h1 is ever needed).
__global__ __launch_bounds__(HIST_THREADS) void k_hist(const int* __restrict__ rows,
                                                       const int* __restrict__ cols,
                                                       const unsigned* __restrict__ bm,
                                                       int* __restrict__ deg2,
                                                       unsigned* __restrict__ flag_bm,
                                                       int* __restrict__ counter,
                                                       int* __restrict__ hsrc, int* __restrict__ hpack,
                                                       unsigned short* __restrict__ rank16,
                                                       unsigned* __restrict__ histw,
                                                       int N, int E, int chunk) {
  extern __shared__ unsigned sh[];
  int WN = (N + 1) >> 1;
  unsigned* hist = sh;                       // WN words (packed u16 pair)
  int* s_src = (int*)(sh + WN);              // [HIST_THREADS]
  int* s_pack = s_src + HIST_THREADS;        // [HIST_THREADS]
  int* s_meta = s_pack + HIST_THREADS;       // [0]=cnt [1]=base
  int tid = threadIdx.x;
  int cidx = blockIdx.x, rel = blockIdx.y;

  for (int i = tid; i < WN; i += HIST_THREADS) hist[i] = 0;
  __syncthreads();

  int estart = cidx * chunk;
  int eend = min(estart + chunk, E);
  for (int eb = estart; eb < eend; eb += HIST_THREADS) {
    if (tid == 0) s_meta[0] = 0;
    __syncthreads();
    int e = eb + tid;
    if (e < eend) {
      int r = rows[rel * E + e];   // layer-1 dest / layer-2 src
      int c = cols[rel * E + e];   // layer-1 src / layer-2 dest
      unsigned old = atomicAdd(&hist[r >> 1], 1u << (16 * (r & 1)));
      rank16[rel * E + e] = (unsigned short)((old >> (16 * (r & 1))) & 0xFFFFu);
      if ((bm[c >> 5] >> (c & 31)) & 1u) {
        atomicAdd(&deg2[rel * N + c], 1);
        atomicOr(&flag_bm[r >> 5], 1u << (r & 31));   // h1[r] will be needed
        int p = atomicAdd(&s_meta[0], 1);
        s_src[p] = r;
        s_pack[p] = (rel << 20) | c;         // N < 2^20
      }
    }
    __syncthreads();
    int cnt = s_meta[0];
    if (tid == 0 && cnt > 0) s_meta[1] = atomicAdd(counter, cnt);
    __syncthreads();
    if (tid < cnt) {
      int b = s_meta[1];
      hsrc[b + tid] = s_src[tid];
      hpack[b + tid] = s_pack[tid];
    }
    __syncthreads();
  }
  unsigned* dst = &histw[(size_t)(rel * HIST_C + cidx) * WN];
  for (int i = tid; i < WN; i += HIST_THREADS) dst[i] = hist[i];
}

// ---------------- reduce copies -> in-place absolute bases + inv-weights ----------------
__global__ __launch_bounds__(256) void k_reduce(unsigned* __restrict__ histw,
                                                const float* __restrict__ a_soft,
                                                float* __restrict__ inv1,
                                                int* __restrict__ rowdeg, int N) {
  int WN = (N + 1) >> 1;
  int t = blockIdx.x * 256 + threadIdx.x;
  if (t >= WN) return;
  int d0 = 2 * t, d1 = 2 * t + 1;
  int tot0 = 0, tot1 = 0;
#pragma unroll
  for (int rel = 0; rel < 3; ++rel) {
    int run0 = tot0, run1 = tot1;
    for (int c = 0; c < HIST_C; ++c) {
      size_t idx = (size_t)(rel * HIST_C + c) * WN + t;
      unsigned w = histw[idx];
      histw[idx] = (unsigned)(run0 & 0xFFFF) | ((unsigned)(run1 & 0xFFFF) << 16);
      run0 += (int)(w & 0xFFFFu);
      run1 += (int)(w >> 16);
    }
    int dg0 = run0 - tot0, dg1 = run1 - tot1;
    float a = a_soft[rel];
    inv1[rel * N + d0] = a / (float)max(dg0, 1);
    if (d1 < N) inv1[rel * N + d1] = a / (float)max(dg1, 1);
    tot0 = run0; tot1 = run1;
  }
  rowdeg[d0] = tot0;
  if (d1 < N) rowdeg[d1] = tot1;
}

// ---------------- prefix sum over rowdeg ----------------

__global__ __launch_bounds__(256) void k_scan1(const int* __restrict__ rowdeg,
                                               int* __restrict__ row_ptr,
                                               int* __restrict__ chunk_sums, int N) {
  __shared__ int sd[256];
  int tid = threadIdx.x;
  int n0 = blockIdx.x * 1024 + tid * 4;
  int v[4];
#pragma unroll
  for (int i = 0; i < 4; ++i) {
    int n = n0 + i;
    v[i] = (n < N) ? rowdeg[n] : 0;
  }
  sd[tid] = v[0] + v[1] + v[2] + v[3];
  __syncthreads();
  for (int off = 1; off < 256; off <<= 1) {
    int t = (tid >= off) ? sd[tid - off] : 0;
    __syncthreads();
    sd[tid] += t;
    __syncthreads();
  }
  int run = tid ? sd[tid - 1] : 0;
#pragma unroll
  for (int i = 0; i < 4; ++i) {
    int n = n0 + i;
    if (n < N) row_ptr[n] = run;
    run += v[i];
  }
  if (tid == 255) chunk_sums[blockIdx.x] = sd[255];
}

__global__ __launch_bounds__(64) void k_scan2(const int* __restrict__ chunk_sums,
                                              int* __restrict__ chunk_offs,
                                              int nchunks, int* __restrict__ row_ptr, int N) {
  int lane = threadIdx.x;
  int mine = (lane < nchunks) ? chunk_sums[lane] : 0;
  int v = mine;
  for (int off = 1; off < 64; off <<= 1) {
    int t = __shfl_up(v, off, 64);
    if (lane >= off) v += t;
  }
  if (lane < nchunks) chunk_offs[lane] = v - mine;
  int total = __shfl(v, nchunks - 1, 64);
  if (lane == 0) row_ptr[N] = total;
}

__global__ __launch_bounds__(256) void k_scan3(int* __restrict__ row_ptr,
                                               const int* __restrict__ chunk_offs, int N) {
  int n = blockIdx.x * 256 + threadIdx.x;
  if (n < N) row_ptr[n] += chunk_offs[n >> 10];
}

// ---------------- atomic-free scatter (only for flagged dests) ----------------

__global__ __launch_bounds__(256) void k_scatter(const int* __restrict__ rows,
                                                 const int* __restrict__ cols,
                                                 const int* __restrict__ row_ptr,
                                                 const unsigned* __restrict__ histw,
                                                 const unsigned short* __restrict__ rank16,
                                                 const unsigned* __restrict__ flag_bm,
                                                 unsigned* __restrict__ esrc,
                                                 int N, int E, int chunk) {
  int e = blockIdx.x * 256 + threadIdx.x;
  int rel = blockIdx.y;
  if (e >= E) return;
  int d = rows[rel * E + e];
  if (!((flag_bm[d >> 5] >> (d & 31)) & 1u)) return;   // h1[d] never consumed
  int s = cols[rel * E + e];
  int WN = (N + 1) >> 1;
  int c = e / chunk;
  const unsigned short* cb = (const unsigned short*)histw;
  int pos = row_ptr[d] + (int)cb[(size_t)(rel * HIST_C + c) * (2 * WN) + d]
          + (int)rank16[rel * E + e];
  esrc[pos] = ((unsigned)rel << 16) | (unsigned)s;   // src < 2^16
}

// ---------------- GEMM1: supp_bf[M][128] = bf16(A[M][K] @ W[K][128] + bias) ----------------

__global__ __launch_bounds__(256) void k_gemm1(const float* __restrict__ A,
                                               const float* __restrict__ W,
                                               const float* __restrict__ bias,
                                               unsigned short* __restrict__ outbf,
                                               int M, int K) {
  __shared__ float sW[64][128];   // 32 KB
  __shared__ float sA[32][64];    // 8 KB
  int tid = threadIdx.x;
  int wave = tid >> 6, lane = tid & 63;
  int lane2 = lane * 2;
  int row0 = blockIdx.x * 32;
  float acc[8][2] = {};
  for (int k0 = 0; k0 < K; k0 += 64) {
    int kc = min(64, K - k0);
    __syncthreads();
    for (int i = tid; i < kc * 32; i += 256) {
      int kk = i >> 5, c4 = i & 31;
      ((float4*)&sW[kk][0])[c4] = ((const float4*)&W[(size_t)(k0 + kk) * 128])[c4];
    }
    int kq4 = kc >> 2;
    for (int i = tid; i < 32 * kq4; i += 256) {
      int r = i / kq4, kq = i - r * kq4;
      int gr = row0 + r;
      float4 v = make_float4(0.f, 0.f, 0.f, 0.f);
      if (gr < M) v = ((const float4*)&A[(size_t)gr * K + k0])[kq];
      ((float4*)&sA[r][0])[kq] = v;
    }
    __syncthreads();
    const float* ap = &sA[wave * 8][0];
    for (int kk = 0; kk < kc; kk += 2) {
      float2 w0 = *(const float2*)&sW[kk][lane2];
      float2 w1 = *(const float2*)&sW[kk + 1][lane2];
#pragma unroll
      for (int r = 0; r < 8; ++r) {
        float2 av = *(const float2*)&ap[r * 64 + kk];
        acc[r][0] += av.x * w0.x + av.y * w1.x;
        acc[r][1] += av.x * w0.y + av.y * w1.y;
      }
    }
  }
  float2 bv = *(const float2*)&bias[lane2];
#pragma unroll
  for (int r = 0; r < 8; ++r) {
    int gr = row0 + wave * 8 + r;
    if (gr < M) {
      __hip_bfloat16 h0 = __float2bfloat16(acc[r][0] + bv.x);
      __hip_bfloat16 h1 = __float2bfloat16(acc[r][1] + bv.y);
      unsigned pk = (unsigned)(*(unsigned short*)&h0) |
                    ((unsigned)(*(unsigned short*)&h1) << 16);
      ((unsigned*)&outbf[(size_t)gr * 128])[lane] = pk;
    }
  }
}

// ---------------- layer-1 aggregation + LeakyReLU + L2 norm (flagged rows only) ----------------

__global__ __launch_bounds__(256) void k_agg_norm(const unsigned short* __restrict__ supp,
                                                  const int* __restrict__ row_ptr,
                                                  const unsigned* __restrict__ esrc,
                                                  const float* __restrict__ inv1,
                                                  const unsigned* __restrict__ flag_bm,
                                                  float* __restrict__ out, int N) {
  int wv = blockIdx.x * 4 + (threadIdx.x >> 6);
  if (wv >= N) return;
  int row = __builtin_amdgcn_readfirstlane(wv);
  if (!((flag_bm[row >> 5] >> (row & 31)) & 1u)) return;   // never consumed
  int lane = threadIdx.x & 63;
  int s = row_ptr[row], e = row_ptr[row + 1];
  float w0 = inv1[row], w1 = inv1[N + row], w2 = inv1[2 * N + row];
  float ax = 0.f, ay = 0.f;
  for (int j = s; j < e; ++j) {
    unsigned u = esrc[j];
    int rel = (int)(u >> 16);
    int src = (int)(u & 0xFFFFu);
    float w = (rel == 0) ? w0 : ((rel == 1) ? w1 : w2);
    unsigned pv = ((const unsigned*)&supp[(size_t)src * 128])[lane];
    float vx = __uint_as_float(pv << 16);
    float vy = __uint_as_float(pv & 0xFFFF0000u);
    ax += w * vx;
    ay += w * vy;
  }
  ax = ax > 0.f ? ax : LEAKY_SLOPE * ax;
  ay = ay > 0.f ? ay : LEAKY_SLOPE * ay;
  float ss = ax * ax + ay * ay;
#pragma unroll
  for (int m = 1; m < 64; m <<= 1) ss += __shfl_xor(ss, m, 64);
  float inv = 1.0f / fmaxf(sqrtf(ss), 1e-12f);
  *(float2*)&out[(size_t)row * 128 + lane * 2] = make_float2(ax * inv, ay * inv);
}

// ---------------- layer-2 small path ----------------
// counts + exclusive scan over label slots (single block; L <= 1024)
__global__ __launch_bounds__(1024) void k_cnt2(const int* __restrict__ lidx,
                                               const int* __restrict__ lab_of,
                                               const int* __restrict__ deg2,
                                               const float* __restrict__ a_soft,
                                               int* __restrict__ hb_ptr,
                                               int* __restrict__ cnt2,
                                               int* __restrict__ fill2,
                                               float* __restrict__ sumw, int N, int L) {
  __shared__ int sd[1024];
  int t = threadIdx.x;
  int cnt = 0;
  if (t < L) {
    int d = lidx[t];
    int c0 = deg2[d], c1 = deg2[N + d], c2 = deg2[2 * N + d];
    if (lab_of[d] == t) cnt = c0 + c1 + c2;       // canonical slot owns the edges
    sumw[t] = a_soft[3] * (c0 > 0 ? 1.f : 0.f) +
              a_soft[4] * (c1 > 0 ? 1.f : 0.f) +
              a_soft[5] * (c2 > 0 ? 1.f : 0.f);
  }
  sd[t] = cnt;
  __syncthreads();
  for (int off = 1; off < 1024; off <<= 1) {
    int v = (t >= off) ? sd[t - off] : 0;
    __syncthreads();
    sd[t] += v;
    __syncthreads();
  }
  if (t < L) {
    int base = sd[t] - cnt;
    hb_ptr[t] = base;
    fill2[t] = base;
    cnt2[t] = cnt;
  }
}

// scatter hit edges into per-label CSR (spread atomics over <=1000 counters)
__global__ __launch_bounds__(256) void k_scatter2(const int* __restrict__ hsrc,
                                                  const int* __restrict__ hpack,
                                                  const int* __restrict__ counter,
                                                  const int* __restrict__ lab_of,
                                                  int* __restrict__ fill2,
                                                  unsigned* __restrict__ hdata) {
  int cnt = counter[0];
  for (int i = blockIdx.x * 256 + threadIdx.x; i < cnt; i += gridDim.x * 256) {
    int src = hsrc[i], pk = hpack[i];
    int rel = pk >> 20, d = pk & 0xFFFFF;
    int li = lab_of[d];
    int pos = atomicAdd(&fill2[li], 1);
    hdata[pos] = ((unsigned)rel << 16) | (unsigned)src;
  }
}

// aggregate h1 rows per canonical label slot: aggh[li] = sum w * h1[src]
__global__ __launch_bounds__(256) void k_agg2(const float* __restrict__ h1,
                                              const int* __restrict__ hb_ptr,
                                              const int* __restrict__ cnt2,
                                              const unsigned* __restrict__ hdata,
                                              const int* __restrict__ lidx,
                                              const int* __restrict__ deg2,
                                              const float* __restrict__ a_soft,
                                              float* __restrict__ aggh, int N, int L) {
  int wv = blockIdx.x * 4 + (threadIdx.x >> 6);
  if (wv >= L) return;
  int li = __builtin_amdgcn_readfirstlane(wv);
  int lane2 = (threadIdx.x & 63) * 2;
  int d = lidx[li];
  int s = hb_ptr[li], cnt = cnt2[li];
  float w0 = a_soft[3] / (float)max(deg2[d], 1);
  float w1 = a_soft[4] / (float)max(deg2[N + d], 1);
  float w2 = a_soft[5] / (float)max(deg2[2 * N + d], 1);
  float ax = 0.f, ay = 0.f;
  for (int j = s; j < s + cnt; ++j) {
    unsigned u = hdata[j];
    int rel = (int)(u >> 16);
    int src = (int)(u & 0xFFFFu);
    float w = (rel == 0) ? w0 : ((rel == 1) ? w1 : w2);
    float2 v = *(const float2*)&h1[(size_t)src * 128 + lane2];
    ax += w * v.x;
    ay += w * v.y;
  }
  *(float2*)&aggh[(size_t)li * 128 + lane2] = make_float2(ax, ay);
}

// final: out[li] = normalize(leaky(aggh[canon(li)] @ W2 + b2*sumw[li]))
__global__ __launch_bounds__(256) void k_final(const float* __restrict__ aggh,
                                               const float* __restrict__ W2,
                                               const float* __restrict__ b2,
                                               const float* __restrict__ sumw,
                                               const int* __restrict__ lidx,
                                               const int* __restrict__ lab_of,
                                               float* __restrict__ out, int L) {
  __shared__ float sW[64][128];   // 32 KB
  __shared__ float sA[32][64];    // 8 KB
  __shared__ int s_c[32];
  __shared__ float s_sw[32];
  int tid = threadIdx.x;
  int wave = tid >> 6, lane = tid & 63;
  int lane2 = lane * 2;
  int row0 = blockIdx.x * 32;
  if (tid < 32) {
    int gr = row0 + tid;
    int c = 0; float sw = 0.f;
    if (gr < L) { c = lab_of[lidx[gr]]; sw = sumw[gr]; }
    s_c[tid] = c; s_sw[tid] = sw;
  }
  __syncthreads();
  float acc[8][2] = {};
  for (int k0 = 0; k0 < 128; k0 += 64) {
    __syncthreads();
    for (int i = tid; i < 64 * 32; i += 256) {
      int kk = i >> 5, c4 = i & 31;
      ((float4*)&sW[kk][0])[c4] = ((const float4*)&W2[(size_t)(k0 + kk) * 128])[c4];
    }
    for (int i = tid; i < 32 * 16; i += 256) {
      int r = i >> 4, kq = i & 15;
      int gr = row0 + r;
      float4 v = make_float4(0.f, 0.f, 0.f, 0.f);
      if (gr < L) v = ((const float4*)&aggh[(size_t)s_c[r] * 128 + k0])[kq];
      ((float4*)&sA[r][0])[kq] = v;
    }
    __syncthreads();
    const float* ap = &sA[wave * 8][0];
    for (int kk = 0; kk < 64; kk += 2) {
      float2 w0 = *(const float2*)&sW[kk][lane2];
      float2 w1 = *(const float2*)&sW[kk + 1][lane2];
#pragma unroll
      for (int r = 0; r < 8; ++r) {
        float2 av = *(const float2*)&ap[r * 64 + kk];
        acc[r][0] += av.x * w0.x + av.y * w1.x;
        acc[r][1] += av.x * w0.y + av.y * w1.y;
      }
    }
  }
  float2 bv = *(const float2*)&b2[lane2];
#pragma unroll
  for (int r = 0; r < 8; ++r) {
    int gr = row0 + wave * 8 + r;
    float sw = s_sw[wave * 8 + r];
    float ax = acc[r][0] + bv.x * sw;
    float ay = acc[r][1] + bv.y * sw;
    ax = ax > 0.f ? ax : LEAKY_SLOPE * ax;
    ay = ay > 0.f ? ay : LEAKY_SLOPE * ay;
    float ss = ax * ax + ay * ay;
#pragma unroll
    for (int m = 1; m < 64; m <<= 1) ss += __shfl_xor(ss, m, 64);
    float inv = 1.0f / fmaxf(sqrtf(ss), 1e-12f);
    if (gr < L) {
      *(float2*)&out[(size_t)gr * 128 + lane2] = make_float2(ax * inv, ay * inv);
    }
  }
}

// ---------------- host ----------------

extern "C" void kernel_launch(void* const* d_in, const int* in_sizes, int n_in,
                              void* d_out, int out_size, void* d_ws, size_t ws_size,
                              hipStream_t stream) {
  const float* feat  = (const float*)d_in[0];
  const float* w1    = (const float*)d_in[1];
  const float* b1    = (const float*)d_in[2];
  const float* w2    = (const float*)d_in[3];
  const float* b2    = (const float*)d_in[4];
  const float* a_att = (const float*)d_in[5];
  const float* r_att = (const float*)d_in[6];
  const int* rows    = (const int*)d_in[7];
  const int* cols    = (const int*)d_in[8];
  const int* lidx    = (const int*)d_in[9];

  const int F = 128;
  int K1 = in_sizes[1] / F;        // 300
  int N  = in_sizes[0] / K1;       // 50000
  int E  = in_sizes[7] / 3;        // 800000
  int L  = in_sizes[9];            // 1000
  float* outp = (float*)d_out;
  (void)n_in; (void)out_size; (void)ws_size;

  int WN = (N + 1) >> 1;
  int chunk = (E + HIST_C - 1) / HIST_C;

  char* base = (char*)d_ws;
  size_t off = 0;
  auto take = [&](size_t bytes) -> void* {
    size_t cur = (off + 255) & ~(size_t)255;
    off = cur + bytes;
    return (void*)(base + cur);
  };
  unsigned short* suppbf = (unsigned short*)take((size_t)N * F * 2);
  float* h1    = (float*)take((size_t)N * F * 4);
  unsigned* esrc = (unsigned*)take((size_t)3 * E * 4);
  unsigned short* rank16 = (unsigned short*)take((size_t)3 * E * 2);
  unsigned* histw = (unsigned*)take((size_t)3 * HIST_C * WN * 4);
  float* inv1  = (float*)take((size_t)3 * N * 4);
  int* rowdeg  = (int*)take((size_t)N * 4);
  int* row_ptr = (int*)take((size_t)(N + 1) * 4);
  int* hsrc  = (int*)take((size_t)1000000 * 4);
  int* hpack = (int*)take((size_t)1000000 * 4);
  unsigned* hdata = (unsigned*)take((size_t)1000000 * 4);
  float* aggh = (float*)take((size_t)1024 * F * 4);
  int* lab_of = (int*)take((size_t)N * 4);
  int nb = (N + 31) / 32;
  int zn = 3 * N + 2 * nb + 1;                  // deg2 + bm + flag_bm + counter
  int* deg2 = (int*)take((size_t)zn * 4);
  unsigned* bm = (unsigned*)(deg2 + 3 * N);
  unsigned* flag_bm = bm + nb;
  int* counter = (int*)(flag_bm + nb);
  int* hb_ptr = (int*)take(1024 * 4);
  int* cnt2   = (int*)take(1024 * 4);
  int* fill2  = (int*)take(1024 * 4);
  float* sumw = (float*)take(1024 * 4);
  float* a_soft = (float*)take(64);
  int* chunk_sums = (int*)take(256);
  int* chunk_offs = (int*)take(256);

  int nchunks = (N + 1023) / 1024;
  size_t shbytes = (size_t)WN * 4 + (size_t)HIST_THREADS * 8 + 16;
  hipFuncSetAttribute((const void*)k_hist, hipFuncAttributeMaxDynamicSharedMemorySize,
                      (int)shbytes);

  hipLaunchKernelGGL(k_zero, dim3((zn + 255) / 256), dim3(256), 0, stream, deg2, zn, 0);
  hipLaunchKernelGGL(k_zero, dim3((N + 255) / 256), dim3(256), 0, stream, lab_of, N, -1);
  hipLaunchKernelGGL(k_softmax3, dim3(1), dim3(64), 0, stream, a_att, r_att, a_soft);
  hipLaunchKernelGGL(k_lab, dim3((L + 255) / 256), dim3(256), 0, stream, lidx, bm, lab_of, L);
  hipLaunchKernelGGL(k_hist, dim3(HIST_C, 3), dim3(HIST_THREADS), shbytes, stream,
                     rows, cols, bm, deg2, flag_bm, counter, hsrc, hpack, rank16, histw,
                     N, E, chunk);
  hipLaunchKernelGGL(k_gemm1, dim3((N + 31) / 32), dim3(256), 0, stream,
                     feat, w1, b1, suppbf, N, K1);
  hipLaunchKernelGGL(k_reduce, dim3((WN + 255) / 256), dim3(256), 0, stream,
                     histw, a_soft, inv1, rowdeg, N);
  hipLaunchKernelGGL(k_scan1, dim3(nchunks), dim3(256), 0, stream, rowdeg, row_ptr, chunk_sums, N);
  hipLaunchKernelGGL(k_scan2, dim3(1), dim3(64), 0, stream, chunk_sums, chunk_offs, nchunks, row_ptr, N);
  hipLaunchKernelGGL(k_scan3, dim3((N + 255) / 256), dim3(256), 0, stream, row_ptr, chunk_offs, N);
  hipLaunchKernelGGL(k_scatter, dim3((E + 255) / 256, 3), dim3(256), 0, stream,
                     rows, cols, row_ptr, histw, rank16, flag_bm, esrc, N, E, chunk);
  hipLaunchKernelGGL(k_agg_norm, dim3((N + 3) / 4), dim3(256), 0, stream,
                     suppbf, row_ptr, esrc, inv1, flag_bm, h1, N);
  hipLaunchKernelGGL(k_cnt2, dim3(1), dim3(1024), 0, stream,
                     lidx, lab_of, deg2, a_soft, hb_ptr, cnt2, fill2, sumw, N, L);
  hipLaunchKernelGGL(k_scatter2, dim3(256), dim3(256), 0, stream,
                     hsrc, hpack, counter, lab_of, fill2, hdata);
  hipLaunchKernelGGL(k_agg2, dim3((L + 3) / 4), dim3(256), 0, stream,
                     h1, hb_ptr, cnt2, hdata, lidx, deg2, a_soft, aggh, N, L);
  hipLaunchKernelGGL(k_final, dim3((L + 31) / 32), dim3(256), 0, stream,
                     aggh, w2, b2, sumw, lidx, lab_of, outp, L);
}

// Round 6
// 363.189 us; speedup vs baseline: 4.7047x; 1.1148x over previous
//
#include <hip/hip_runtime.h>
#include <hip/hip_bf16.h>

#define LEAKY_SLOPE 0.2f
#define HIST_C 85          // chunks per relation for privatized histogram
#define HIST_THREADS 1024
#define KP 320             // K=300 padded to 320 for MFMA

typedef __attribute__((ext_vector_type(8))) short bf16x8;
typedef __attribute__((ext_vector_type(4))) float f32x4;

__device__ __forceinline__ unsigned short f2bf(float f) {
  __hip_bfloat16 h = __float2bfloat16(f);   // RNE
  return *(unsigned short*)&h;
}
__device__ __forceinline__ float bf2f(unsigned short u) {
  return __uint_as_float(((unsigned)u) << 16);
}

// ---------------- utility kernels ----------------

__global__ __launch_bounds__(256) void k_zero(int* __restrict__ p, int n, int val) {
  int i = blockIdx.x * 256 + threadIdx.x;
  if (i < n) p[i] = val;
}

__global__ __launch_bounds__(64) void k_softmax3(const float* __restrict__ a_att,
                                                 const float* __restrict__ r_att,
                                                 float* __restrict__ a_soft) {
  if (threadIdx.x == 0) {
    float m = fmaxf(fmaxf(a_att[0], a_att[1]), a_att[2]);
    float e0 = expf(a_att[0] - m), e1 = expf(a_att[1] - m), e2 = expf(a_att[2] - m);
    float s = 1.0f / (e0 + e1 + e2);
    a_soft[0] = e0 * s; a_soft[1] = e1 * s; a_soft[2] = e2 * s;
    m = fmaxf(fmaxf(r_att[0], r_att[1]), r_att[2]);
    e0 = expf(r_att[0] - m); e1 = expf(r_att[1] - m); e2 = expf(r_att[2] - m);
    s = 1.0f / (e0 + e1 + e2);
    a_soft[3] = e0 * s; a_soft[4] = e1 * s; a_soft[5] = e2 * s;
  }
}

// label bitmap + canonical slot map (deterministic via atomicMax; handles dup labels)
__global__ __launch_bounds__(256) void k_lab(const int* __restrict__ lidx,
                                             unsigned* __restrict__ bm,
                                             int* __restrict__ lab_of, int L) {
  int i = blockIdx.x * 256 + threadIdx.x;
  if (i < L) {
    int n = lidx[i];
    atomicOr(&bm[n >> 5], 1u << (n & 31));
    atomicMax(&lab_of[n], i);
  }
}

// W1 (f32 [K][128]) -> transposed, K-padded hi/lo bf16 [128][KP]
__global__ __launch_bounds__(256) void k_prep(const float* __restrict__ w1,
                                              unsigned short* __restrict__ WThi,
                                              unsigned short* __restrict__ WTlo, int K) {
  int i = blockIdx.x * 256 + threadIdx.x;
  if (i >= 128 * KP) return;
  int n = i / KP, k = i - n * KP;
  float f = (k < K) ? w1[(size_t)k * 128 + n] : 0.f;
  unsigned short hi = f2bf(f);
  unsigned short lo = f2bf(f - bf2f(hi));
  WThi[i] = hi;
  WTlo[i] = lo;
}

// ---------------- LDS-privatized histogram + rank assignment ----------------
// grid (HIST_C, 3). Packed-u16 LDS histogram; LDS atomic return = local rank.
// Hit records go to a per-block PRIVATE region (base = region*chunk, local LDS
// counter) -> zero global counter atomics, zero per-batch barriers.
__global__ __launch_bounds__(HIST_THREADS) void k_hist(const int* __restrict__ rows,
                                                       const int* __restrict__ cols,
                                                       const unsigned* __restrict__ bm,
                                                       int* __restrict__ deg2,
                                                       unsigned* __restrict__ flag_bm,
                                                       int* __restrict__ hcnt,
                                                       int* __restrict__ hsrc, int* __restrict__ hpack,
                                                       unsigned short* __restrict__ rank16,
                                                       unsigned* __restrict__ histw,
                                                       int N, int E, int chunk) {
  extern __shared__ unsigned sh[];
  __shared__ int s_cnt;
  int WN = (N + 1) >> 1;
  unsigned* hist = sh;                       // WN words (packed u16 pair)
  int tid = threadIdx.x;
  int cidx = blockIdx.x, rel = blockIdx.y;

  for (int i = tid; i < WN; i += HIST_THREADS) hist[i] = 0;
  if (tid == 0) s_cnt = 0;
  __syncthreads();

  int estart = cidx * chunk;
  int eend = min(estart + chunk, E);
  int rbase = (rel * HIST_C + cidx) * chunk;
  for (int e = estart + tid; e < eend; e += HIST_THREADS) {
    int r = rows[rel * E + e];   // layer-1 dest / layer-2 src
    int c = cols[rel * E + e];   // layer-1 src / layer-2 dest
    unsigned old = atomicAdd(&hist[r >> 1], 1u << (16 * (r & 1)));
    rank16[rel * E + e] = (unsigned short)((old >> (16 * (r & 1))) & 0xFFFFu);
    if ((bm[c >> 5] >> (c & 31)) & 1u) {
      atomicAdd(&deg2[rel * N + c], 1);
      atomicOr(&flag_bm[r >> 5], 1u << (r & 31));   // h1[r] will be needed
      int p = atomicAdd(&s_cnt, 1);                 // LDS atomic, on-CU
      hsrc[rbase + p] = r;
      hpack[rbase + p] = (rel << 20) | c;           // N < 2^20
    }
  }
  __syncthreads();
  if (tid == 0) hcnt[rel * HIST_C + cidx] = s_cnt;
  unsigned* dst = &histw[(size_t)(rel * HIST_C + cidx) * WN];
  for (int i = tid; i < WN; i += HIST_THREADS) dst[i] = hist[i];
}

// ---------------- reduce copies -> in-place absolute bases + inv-weights ----------------
__global__ __launch_bounds__(256) void k_reduce(unsigned* __restrict__ histw,
                                                const float* __restrict__ a_soft,
                                                float* __restrict__ inv1,
                                                int* __restrict__ rowdeg, int N) {
  int WN = (N + 1) >> 1;
  int t = blockIdx.x * 256 + threadIdx.x;
  if (t >= WN) return;
  int d0 = 2 * t, d1 = 2 * t + 1;
  int tot0 = 0, tot1 = 0;
#pragma unroll
  for (int rel = 0; rel < 3; ++rel) {
    int run0 = tot0, run1 = tot1;
    for (int c = 0; c < HIST_C; ++c) {
      size_t idx = (size_t)(rel * HIST_C + c) * WN + t;
      unsigned w = histw[idx];
      histw[idx] = (unsigned)(run0 & 0xFFFF) | ((unsigned)(run1 & 0xFFFF) << 16);
      run0 += (int)(w & 0xFFFFu);
      run1 += (int)(w >> 16);
    }
    int dg0 = run0 - tot0, dg1 = run1 - tot1;
    float a = a_soft[rel];
    inv1[rel * N + d0] = a / (float)max(dg0, 1);
    if (d1 < N) inv1[rel * N + d1] = a / (float)max(dg1, 1);
    tot0 = run0; tot1 = run1;
  }
  rowdeg[d0] = tot0;
  if (d1 < N) rowdeg[d1] = tot1;
}

// ---------------- prefix sum over rowdeg ----------------

__global__ __launch_bounds__(256) void k_scan1(const int* __restrict__ rowdeg,
                                               int* __restrict__ row_ptr,
                                               int* __restrict__ chunk_sums, int N) {
  __shared__ int sd[256];
  int tid = threadIdx.x;
  int n0 = blockIdx.x * 1024 + tid * 4;
  int v[4];
#pragma unroll
  for (int i = 0; i < 4; ++i) {
    int n = n0 + i;
    v[i] = (n < N) ? rowdeg[n] : 0;
  }
  sd[tid] = v[0] + v[1] + v[2] + v[3];
  __syncthreads();
  for (int off = 1; off < 256; off <<= 1) {
    int t = (tid >= off) ? sd[tid - off] : 0;
    __syncthreads();
    sd[tid] += t;
    __syncthreads();
  }
  int run = tid ? sd[tid - 1] : 0;
#pragma unroll
  for (int i = 0; i < 4; ++i) {
    int n = n0 + i;
    if (n < N) row_ptr[n] = run;
    run += v[i];
  }
  if (tid == 255) chunk_sums[blockIdx.x] = sd[255];
}

__global__ __launch_bounds__(64) void k_scan2(const int* __restrict__ chunk_sums,
                                              int* __restrict__ chunk_offs,
                                              int nchunks, int* __restrict__ row_ptr, int N) {
  int lane = threadIdx.x;
  int mine = (lane < nchunks) ? chunk_sums[lane] : 0;
  int v = mine;
  for (int off = 1; off < 64; off <<= 1) {
    int t = __shfl_up(v, off, 64);
    if (lane >= off) v += t;
  }
  if (lane < nchunks) chunk_offs[lane] = v - mine;
  int total = __shfl(v, nchunks - 1, 64);
  if (lane == 0) row_ptr[N] = total;
}

__global__ __launch_bounds__(256) void k_scan3(int* __restrict__ row_ptr,
                                               const int* __restrict__ chunk_offs, int N) {
  int n = blockIdx.x * 256 + threadIdx.x;
  if (n < N) row_ptr[n] += chunk_offs[n >> 10];
}

// ---------------- atomic-free scatter (only for flagged dests) ----------------

__global__ __launch_bounds__(256) void k_scatter(const int* __restrict__ rows,
                                                 const int* __restrict__ cols,
                                                 const int* __restrict__ row_ptr,
                                                 const unsigned* __restrict__ histw,
                                                 const unsigned short* __restrict__ rank16,
                                                 const unsigned* __restrict__ flag_bm,
                                                 unsigned* __restrict__ esrc,
                                                 int N, int E, int chunk) {
  int e = blockIdx.x * 256 + threadIdx.x;
  int rel = blockIdx.y;
  if (e >= E) return;
  int d = rows[rel * E + e];
  if (!((flag_bm[d >> 5] >> (d & 31)) & 1u)) return;   // h1[d] never consumed
  int s = cols[rel * E + e];
  int WN = (N + 1) >> 1;
  int c = e / chunk;
  const unsigned short* cb = (const unsigned short*)histw;
  int pos = row_ptr[d] + (int)cb[(size_t)(rel * HIST_C + c) * (2 * WN) + d]
          + (int)rank16[rel * E + e];
  esrc[pos] = ((unsigned)rel << 16) | (unsigned)s;   // src < 2^16
}

// ---------------- GEMM1 via MFMA (hi/lo bf16 split, f32-grade accuracy) ----------------
// block = 64 rows x 128 cols, 256 threads (4 waves), wave = 16 rows x 128 cols.
// K chunked by 64 (5 chunks, last zero-padded). S = Ahi*Whi + Ahi*Wlo + Alo*Whi.

__global__ __launch_bounds__(256) void k_gemm1(const float* __restrict__ A,
                                               const unsigned short* __restrict__ WThi,
                                               const unsigned short* __restrict__ WTlo,
                                               const float* __restrict__ bias,
                                               unsigned short* __restrict__ outbf,
                                               int M, int K) {
  __shared__ unsigned short sAhi[64 * 64], sAlo[64 * 64];     // 8 KB each
  __shared__ unsigned short sWhi[128 * 64], sWlo[128 * 64];   // 16 KB each
  char* pAhi = (char*)sAhi; char* pAlo = (char*)sAlo;
  char* pWhi = (char*)sWhi; char* pWlo = (char*)sWlo;
  int tid = threadIdx.x;
  int wave = tid >> 6, lane = tid & 63;
  int row0 = blockIdx.x * 64;
  f32x4 acc[8];
#pragma unroll
  for (int i = 0; i < 8; ++i) acc[i] = (f32x4){0.f, 0.f, 0.f, 0.f};

  for (int c = 0; c < 5; ++c) {
    int k0 = c * 64;
    __syncthreads();
    // stage A (f32 -> hi/lo bf16), rows x 16 quads of 4 floats
    for (int i = tid; i < 1024; i += 256) {
      int r = i >> 4, q = i & 15;
      int gr = row0 + r, gk = k0 + q * 4;
      float4 v = make_float4(0.f, 0.f, 0.f, 0.f);
      if (gr < M && gk < K) v = *(const float4*)&A[(size_t)gr * K + gk];
      unsigned hh[2], ll[2];
      const float* vp = &v.x;
#pragma unroll
      for (int j = 0; j < 2; ++j) {
        unsigned short h0 = f2bf(vp[2 * j]),     h1 = f2bf(vp[2 * j + 1]);
        unsigned short l0 = f2bf(vp[2 * j] - bf2f(h0));
        unsigned short l1 = f2bf(vp[2 * j + 1] - bf2f(h1));
        hh[j] = (unsigned)h0 | ((unsigned)h1 << 16);
        ll[j] = (unsigned)l0 | ((unsigned)l1 << 16);
      }
      int byte = (r * 128 + q * 8) ^ ((r & 7) << 4);
      *(uint2*)(pAhi + byte) = make_uint2(hh[0], hh[1]);
      *(uint2*)(pAlo + byte) = make_uint2(ll[0], ll[1]);
    }
    // stage WT hi/lo (already bf16, padded): 128 rows x 4 16B units
    for (int i = tid; i < 1024; i += 256) {
      int n = i >> 3, u = i & 7;
      size_t g = (size_t)n * KP + k0 + u * 8;
      int byte = (n * 128 + u * 16) ^ ((n & 7) << 4);
      *(uint4*)(pWhi + byte) = *(const uint4*)&WThi[g];
      *(uint4*)(pWlo + byte) = *(const uint4*)&WTlo[g];
    }
    __syncthreads();
#pragma unroll
    for (int ks = 0; ks < 2; ++ks) {
      int m = wave * 16 + (lane & 15);
      int kb = ks * 32 + (lane >> 4) * 8;
      bf16x8 ahi = *(const bf16x8*)(pAhi + ((m * 128 + kb * 2) ^ ((m & 7) << 4)));
      bf16x8 alo = *(const bf16x8*)(pAlo + ((m * 128 + kb * 2) ^ ((m & 7) << 4)));
#pragma unroll
      for (int nt = 0; nt < 8; ++nt) {
        int n = nt * 16 + (lane & 15);
        int wb = (n * 128 + kb * 2) ^ ((n & 7) << 4);
        bf16x8 bhi = *(const bf16x8*)(pWhi + wb);
        bf16x8 blo = *(const bf16x8*)(pWlo + wb);
        acc[nt] = __builtin_amdgcn_mfma_f32_16x16x32_bf16(ahi, bhi, acc[nt], 0, 0, 0);
        acc[nt] = __builtin_amdgcn_mfma_f32_16x16x32_bf16(ahi, blo, acc[nt], 0, 0, 0);
        acc[nt] = __builtin_amdgcn_mfma_f32_16x16x32_bf16(alo, bhi, acc[nt], 0, 0, 0);
      }
    }
  }
  // epilogue: D[m][n] -> lane: n = nt*16 + (lane&15), m = (lane>>4)*4 + j
#pragma unroll
  for (int nt = 0; nt < 8; ++nt) {
    int n = nt * 16 + (lane & 15);
    float bv = bias[n];
#pragma unroll
    for (int j = 0; j < 4; ++j) {
      int m = row0 + wave * 16 + (lane >> 4) * 4 + j;
      if (m < M) outbf[(size_t)m * 128 + n] = f2bf(acc[nt][j] + bv);
    }
  }
}

// ---------------- layer-1 aggregation + LeakyReLU + L2 norm (flagged rows only) ----------------

__global__ __launch_bounds__(256) void k_agg_norm(const unsigned short* __restrict__ supp,
                                                  const int* __restrict__ row_ptr,
                                                  const unsigned* __restrict__ esrc,
                                                  const float* __restrict__ inv1,
                                                  const unsigned* __restrict__ flag_bm,
                                                  float* __restrict__ out, int N) {
  int wv = blockIdx.x * 4 + (threadIdx.x >> 6);
  if (wv >= N) return;
  int row = __builtin_amdgcn_readfirstlane(wv);
  if (!((flag_bm[row >> 5] >> (row & 31)) & 1u)) return;   // never consumed
  int lane = threadIdx.x & 63;
  int s = row_ptr[row], e = row_ptr[row + 1];
  float w0 = inv1[row], w1 = inv1[N + row], w2 = inv1[2 * N + row];
  float ax = 0.f, ay = 0.f;
  for (int j = s; j < e; ++j) {
    unsigned u = esrc[j];
    int rel = (int)(u >> 16);
    int src = (int)(u & 0xFFFFu);
    float w = (rel == 0) ? w0 : ((rel == 1) ? w1 : w2);
    unsigned pv = ((const unsigned*)&supp[(size_t)src * 128])[lane];
    float vx = __uint_as_float(pv << 16);
    float vy = __uint_as_float(pv & 0xFFFF0000u);
    ax += w * vx;
    ay += w * vy;
  }
  ax = ax > 0.f ? ax : LEAKY_SLOPE * ax;
  ay = ay > 0.f ? ay : LEAKY_SLOPE * ay;
  float ss = ax * ax + ay * ay;
#pragma unroll
  for (int m = 1; m < 64; m <<= 1) ss += __shfl_xor(ss, m, 64);
  float inv = 1.0f / fmaxf(sqrtf(ss), 1e-12f);
  *(float2*)&out[(size_t)row * 128 + lane * 2] = make_float2(ax * inv, ay * inv);
}

// ---------------- layer-2 small path ----------------
__global__ __launch_bounds__(1024) void k_cnt2(const int* __restrict__ lidx,
                                               const int* __restrict__ lab_of,
                                               const int* __restrict__ deg2,
                                               const float* __restrict__ a_soft,
                                               int* __restrict__ hb_ptr,
                                               int* __restrict__ cnt2,
                                               int* __restrict__ fill2,
                                               float* __restrict__ sumw, int N, int L) {
  __shared__ int sd[1024];
  int t = threadIdx.x;
  int cnt = 0;
  if (t < L) {
    int d = lidx[t];
    int c0 = deg2[d], c1 = deg2[N + d], c2 = deg2[2 * N + d];
    if (lab_of[d] == t) cnt = c0 + c1 + c2;       // canonical slot owns the edges
    sumw[t] = a_soft[3] * (c0 > 0 ? 1.f : 0.f) +
              a_soft[4] * (c1 > 0 ? 1.f : 0.f) +
              a_soft[5] * (c2 > 0 ? 1.f : 0.f);
  }
  sd[t] = cnt;
  __syncthreads();
  for (int off = 1; off < 1024; off <<= 1) {
    int v = (t >= off) ? sd[t - off] : 0;
    __syncthreads();
    sd[t] += v;
    __syncthreads();
  }
  if (t < L) {
    int base = sd[t] - cnt;
    hb_ptr[t] = base;
    fill2[t] = base;
    cnt2[t] = cnt;
  }
}

// walk the 3*HIST_C private hit regions -> per-label CSR (atomics spread over <=1000)
__global__ __launch_bounds__(256) void k_scatter2(const int* __restrict__ hsrc,
                                                  const int* __restrict__ hpack,
                                                  const int* __restrict__ hcnt,
                                                  const int* __restrict__ lab_of,
                                                  int* __restrict__ fill2,
                                                  unsigned* __restrict__ hdata, int chunk) {
  int reg = blockIdx.x;
  int cnt = hcnt[reg];
  int rbase = reg * chunk;
  for (int i = threadIdx.x; i < cnt; i += 256) {
    int src = hsrc[rbase + i], pk = hpack[rbase + i];
    int rel = pk >> 20, d = pk & 0xFFFFF;
    int li = lab_of[d];
    int pos = atomicAdd(&fill2[li], 1);
    hdata[pos] = ((unsigned)rel << 16) | (unsigned)src;
  }
}

// aggregate h1 rows per canonical label slot: aggh[li] = sum w * h1[src]
__global__ __launch_bounds__(256) void k_agg2(const float* __restrict__ h1,
                                              const int* __restrict__ hb_ptr,
                                              const int* __restrict__ cnt2,
                                              const unsigned* __restrict__ hdata,
                                              const int* __restrict__ lidx,
                                              const int* __restrict__ deg2,
                                              const float* __restrict__ a_soft,
                                              float* __restrict__ aggh, int N, int L) {
  int wv = blockIdx.x * 4 + (threadIdx.x >> 6);
  if (wv >= L) return;
  int li = __builtin_amdgcn_readfirstlane(wv);
  int lane2 = (threadIdx.x & 63) * 2;
  int d = lidx[li];
  int s = hb_ptr[li], cnt = cnt2[li];
  float w0 = a_soft[3] / (float)max(deg2[d], 1);
  float w1 = a_soft[4] / (float)max(deg2[N + d], 1);
  float w2 = a_soft[5] / (float)max(deg2[2 * N + d], 1);
  float ax = 0.f, ay = 0.f;
  for (int j = s; j < s + cnt; ++j) {
    unsigned u = hdata[j];
    int rel = (int)(u >> 16);
    int src = (int)(u & 0xFFFFu);
    float w = (rel == 0) ? w0 : ((rel == 1) ? w1 : w2);
    float2 v = *(const float2*)&h1[(size_t)src * 128 + lane2];
    ax += w * v.x;
    ay += w * v.y;
  }
  *(float2*)&aggh[(size_t)li * 128 + lane2] = make_float2(ax, ay);
}

// final: out[li] = normalize(leaky(aggh[canon(li)] @ W2 + b2*sumw[li]))
__global__ __launch_bounds__(256) void k_final(const float* __restrict__ aggh,
                                               const float* __restrict__ W2,
                                               const float* __restrict__ b2,
                                               const float* __restrict__ sumw,
                                               const int* __restrict__ lidx,
                                               const int* __restrict__ lab_of,
                                               float* __restrict__ out, int L) {
  __shared__ float sW[64][128];   // 32 KB
  __shared__ float sA[32][64];    // 8 KB
  __shared__ int s_c[32];
  __shared__ float s_sw[32];
  int tid = threadIdx.x;
  int wave = tid >> 6, lane = tid & 63;
  int lane2 = lane * 2;
  int row0 = blockIdx.x * 32;
  if (tid < 32) {
    int gr = row0 + tid;
    int c = 0; float sw = 0.f;
    if (gr < L) { c = lab_of[lidx[gr]]; sw = sumw[gr]; }
    s_c[tid] = c; s_sw[tid] = sw;
  }
  __syncthreads();
  float acc[8][2] = {};
  for (int k0 = 0; k0 < 128; k0 += 64) {
    __syncthreads();
    for (int i = tid; i < 64 * 32; i += 256) {
      int kk = i >> 5, c4 = i & 31;
      ((float4*)&sW[kk][0])[c4] = ((const float4*)&W2[(size_t)(k0 + kk) * 128])[c4];
    }
    for (int i = tid; i < 32 * 16; i += 256) {
      int r = i >> 4, kq = i & 15;
      int gr = row0 + r;
      float4 v = make_float4(0.f, 0.f, 0.f, 0.f);
      if (gr < L) v = ((const float4*)&aggh[(size_t)s_c[r] * 128 + k0])[kq];
      ((float4*)&sA[r][0])[kq] = v;
    }
    __syncthreads();
    const float* ap = &sA[wave * 8][0];
    for (int kk = 0; kk < 64; kk += 2) {
      float2 w0 = *(const float2*)&sW[kk][lane2];
      float2 w1 = *(const float2*)&sW[kk + 1][lane2];
#pragma unroll
      for (int r = 0; r < 8; ++r) {
        float2 av = *(const float2*)&ap[r * 64 + kk];
        acc[r][0] += av.x * w0.x + av.y * w1.x;
        acc[r][1] += av.x * w0.y + av.y * w1.y;
      }
    }
  }
  float2 bv = *(const float2*)&b2[lane2];
#pragma unroll
  for (int r = 0; r < 8; ++r) {
    int gr = row0 + wave * 8 + r;
    float sw = s_sw[wave * 8 + r];
    float ax = acc[r][0] + bv.x * sw;
    float ay = acc[r][1] + bv.y * sw;
    ax = ax > 0.f ? ax : LEAKY_SLOPE * ax;
    ay = ay > 0.f ? ay : LEAKY_SLOPE * ay;
    float ss = ax * ax + ay * ay;
#pragma unroll
    for (int m = 1; m < 64; m <<= 1) ss += __shfl_xor(ss, m, 64);
    float inv = 1.0f / fmaxf(sqrtf(ss), 1e-12f);
    if (gr < L) {
      *(float2*)&out[(size_t)gr * 128 + lane2] = make_float2(ax * inv, ay * inv);
    }
  }
}

// ---------------- host ----------------

extern "C" void kernel_launch(void* const* d_in, const int* in_sizes, int n_in,
                              void* d_out, int out_size, void* d_ws, size_t ws_size,
                              hipStream_t stream) {
  const float* feat  = (const float*)d_in[0];
  const float* w1    = (const float*)d_in[1];
  const float* b1    = (const float*)d_in[2];
  const float* w2    = (const float*)d_in[3];
  const float* b2    = (const float*)d_in[4];
  const float* a_att = (const float*)d_in[5];
  const float* r_att = (const float*)d_in[6];
  const int* rows    = (const int*)d_in[7];
  const int* cols    = (const int*)d_in[8];
  const int* lidx    = (const int*)d_in[9];

  const int F = 128;
  int K1 = in_sizes[1] / F;        // 300
  int N  = in_sizes[0] / K1;       // 50000
  int E  = in_sizes[7] / 3;        // 800000
  int L  = in_sizes[9];            // 1000
  float* outp = (float*)d_out;
  (void)n_in; (void)out_size; (void)ws_size;

  int WN = (N + 1) >> 1;
  int chunk = (E + HIST_C - 1) / HIST_C;

  char* base = (char*)d_ws;
  size_t off = 0;
  auto take = [&](size_t bytes) -> void* {
    size_t cur = (off + 255) & ~(size_t)255;
    off = cur + bytes;
    return (void*)(base + cur);
  };
  unsigned short* suppbf = (unsigned short*)take((size_t)N * F * 2);
  float* h1    = (float*)take((size_t)N * F * 4);
  unsigned* esrc = (unsigned*)take((size_t)3 * E * 4);     // reused as hdata later
  unsigned short* rank16 = (unsigned short*)take((size_t)3 * E * 2);
  unsigned* histw = (unsigned*)take((size_t)3 * HIST_C * WN * 4);
  float* inv1  = (float*)take((size_t)3 * N * 4);
  int* rowdeg  = (int*)take((size_t)N * 4);
  int* row_ptr = (int*)take((size_t)(N + 1) * 4);
  int* hsrc  = (int*)take((size_t)3 * HIST_C * chunk * 4);
  int* hpack = (int*)take((size_t)3 * HIST_C * chunk * 4);
  unsigned short* WThi = (unsigned short*)take((size_t)128 * KP * 2);
  unsigned short* WTlo = (unsigned short*)take((size_t)128 * KP * 2);
  float* aggh = (float*)take((size_t)1024 * F * 4);
  int* lab_of = (int*)take((size_t)N * 4);
  int nb = (N + 31) / 32;
  int zn = 3 * N + 2 * nb;                      // deg2 + bm + flag_bm
  int* deg2 = (int*)take((size_t)zn * 4);
  unsigned* bm = (unsigned*)(deg2 + 3 * N);
  unsigned* flag_bm = bm + nb;
  int* hcnt = (int*)take((size_t)(3 * HIST_C + 1) * 4);
  int* hb_ptr = (int*)take(1024 * 4);
  int* cnt2   = (int*)take(1024 * 4);
  int* fill2  = (int*)take(1024 * 4);
  float* sumw = (float*)take(1024 * 4);
  float* a_soft = (float*)take(64);
  int* chunk_sums = (int*)take(256);
  int* chunk_offs = (int*)take(256);
  unsigned* hdata = esrc;   // esrc is dead after k_agg_norm

  int nchunks = (N + 1023) / 1024;
  size_t shbytes = (size_t)WN * 4;
  hipFuncSetAttribute((const void*)k_hist, hipFuncAttributeMaxDynamicSharedMemorySize,
                      (int)shbytes);

  hipLaunchKernelGGL(k_zero, dim3((zn + 255) / 256), dim3(256), 0, stream, deg2, zn, 0);
  hipLaunchKernelGGL(k_zero, dim3((N + 255) / 256), dim3(256), 0, stream, lab_of, N, -1);
  hipLaunchKernelGGL(k_softmax3, dim3(1), dim3(64), 0, stream, a_att, r_att, a_soft);
  hipLaunchKernelGGL(k_lab, dim3((L + 255) / 256), dim3(256), 0, stream, lidx, bm, lab_of, L);
  hipLaunchKernelGGL(k_prep, dim3((128 * KP + 255) / 256), dim3(256), 0, stream,
                     w1, WThi, WTlo, K1);
  hipLaunchKernelGGL(k_hist, dim3(HIST_C, 3), dim3(HIST_THREADS), shbytes, stream,
                     rows, cols, bm, deg2, flag_bm, hcnt, hsrc, hpack, rank16, histw,
                     N, E, chunk);
  hipLaunchKernelGGL(k_gemm1, dim3((N + 63) / 64), dim3(256), 0, stream,
                     feat, WThi, WTlo, b1, suppbf, N, K1);
  hipLaunchKernelGGL(k_reduce, dim3((WN + 255) / 256), dim3(256), 0, stream,
                     histw, a_soft, inv1, rowdeg, N);
  hipLaunchKernelGGL(k_scan1, dim3(nchunks), dim3(256), 0, stream, rowdeg, row_ptr, chunk_sums, N);
  hipLaunchKernelGGL(k_scan2, dim3(1), dim3(64), 0, stream, chunk_sums, chunk_offs, nchunks, row_ptr, N);
  hipLaunchKernelGGL(k_scan3, dim3((N + 255) / 256), dim3(256), 0, stream, row_ptr, chunk_offs, N);
  hipLaunchKernelGGL(k_scatter, dim3((E + 255) / 256, 3), dim3(256), 0, stream,
                     rows, cols, row_ptr, histw, rank16, flag_bm, esrc, N, E, chunk);
  hipLaunchKernelGGL(k_agg_norm, dim3((N + 3) / 4), dim3(256), 0, stream,
                     suppbf, row_ptr, esrc, inv1, flag_bm, h1, N);
  hipLaunchKernelGGL(k_cnt2, dim3(1), dim3(1024), 0, stream,
                     lidx, lab_of, deg2, a_soft, hb_ptr, cnt2, fill2, sumw, N, L);
  hipLaunchKernelGGL(k_scatter2, dim3(3 * HIST_C), dim3(256), 0, stream,
                     hsrc, hpack, hcnt, lab_of, fill2, hdata, chunk);
  hipLaunchKernelGGL(k_agg2, dim3((L + 3) / 4), dim3(256), 0, stream,
                     h1, hb_ptr, cnt2, hdata, lidx, deg2, a_soft, aggh, N, L);
  hipLaunchKernelGGL(k_final, dim3((L + 31) / 32), dim3(256), 0, stream,
                     aggh, w2, b2, sumw, lidx, lab_of, outp, L);
}

// Round 7
// 308.966 us; speedup vs baseline: 5.5303x; 1.1755x over previous
//
#include <hip/hip_runtime.h>
#include <hip/hip_bf16.h>

#define LEAKY_SLOPE 0.2f
#define HIST_C 85          // chunks per relation for privatized histogram
#define HIST_THREADS 1024
#define KP 320             // K=300 padded to 320 for MFMA

typedef __attribute__((ext_vector_type(8))) short bf16x8;
typedef __attribute__((ext_vector_type(4))) float f32x4;

__device__ __forceinline__ unsigned short f2bf(float f) {
  __hip_bfloat16 h = __float2bfloat16(f);   // RNE
  return *(unsigned short*)&h;
}
__device__ __forceinline__ float bf2f(unsigned short u) {
  return __uint_as_float(((unsigned)u) << 16);
}

// ---------------- utility kernels ----------------

__global__ __launch_bounds__(256) void k_zero(int* __restrict__ p, int n, int val) {
  int i = blockIdx.x * 256 + threadIdx.x;
  if (i < n) p[i] = val;
}

__global__ __launch_bounds__(64) void k_softmax3(const float* __restrict__ a_att,
                                                 const float* __restrict__ r_att,
                                                 float* __restrict__ a_soft) {
  if (threadIdx.x == 0) {
    float m = fmaxf(fmaxf(a_att[0], a_att[1]), a_att[2]);
    float e0 = expf(a_att[0] - m), e1 = expf(a_att[1] - m), e2 = expf(a_att[2] - m);
    float s = 1.0f / (e0 + e1 + e2);
    a_soft[0] = e0 * s; a_soft[1] = e1 * s; a_soft[2] = e2 * s;
    m = fmaxf(fmaxf(r_att[0], r_att[1]), r_att[2]);
    e0 = expf(r_att[0] - m); e1 = expf(r_att[1] - m); e2 = expf(r_att[2] - m);
    s = 1.0f / (e0 + e1 + e2);
    a_soft[3] = e0 * s; a_soft[4] = e1 * s; a_soft[5] = e2 * s;
  }
}

// label bitmap + canonical slot map (deterministic via atomicMax; handles dup labels)
__global__ __launch_bounds__(256) void k_lab(const int* __restrict__ lidx,
                                             unsigned* __restrict__ bm,
                                             int* __restrict__ lab_of, int L) {
  int i = blockIdx.x * 256 + threadIdx.x;
  if (i < L) {
    int n = lidx[i];
    atomicOr(&bm[n >> 5], 1u << (n & 31));
    atomicMax(&lab_of[n], i);
  }
}

// W1 (f32 [K][128]) -> transposed, K-padded hi/lo bf16 [128][KP]
__global__ __launch_bounds__(256) void k_prep(const float* __restrict__ w1,
                                              unsigned short* __restrict__ WThi,
                                              unsigned short* __restrict__ WTlo, int K) {
  int i = blockIdx.x * 256 + threadIdx.x;
  if (i >= 128 * KP) return;
  int n = i / KP, k = i - n * KP;
  float f = (k < K) ? w1[(size_t)k * 128 + n] : 0.f;
  unsigned short hi = f2bf(f);
  unsigned short lo = f2bf(f - bf2f(hi));
  WThi[i] = hi;
  WTlo[i] = lo;
}

// ---------------- LDS-privatized histogram + rank assignment ----------------
__global__ __launch_bounds__(HIST_THREADS) void k_hist(const int* __restrict__ rows,
                                                       const int* __restrict__ cols,
                                                       const unsigned* __restrict__ bm,
                                                       int* __restrict__ deg2,
                                                       unsigned* __restrict__ flag_bm,
                                                       int* __restrict__ hcnt,
                                                       int* __restrict__ hsrc, int* __restrict__ hpack,
                                                       unsigned short* __restrict__ rank16,
                                                       unsigned* __restrict__ histw,
                                                       int N, int E, int chunk) {
  extern __shared__ unsigned sh[];
  __shared__ int s_cnt;
  int WN = (N + 1) >> 1;
  unsigned* hist = sh;                       // WN words (packed u16 pair)
  int tid = threadIdx.x;
  int cidx = blockIdx.x, rel = blockIdx.y;

  for (int i = tid; i < WN; i += HIST_THREADS) hist[i] = 0;
  if (tid == 0) s_cnt = 0;
  __syncthreads();

  int estart = cidx * chunk;
  int eend = min(estart + chunk, E);
  int rbase = (rel * HIST_C + cidx) * chunk;
  for (int e = estart + tid; e < eend; e += HIST_THREADS) {
    int r = rows[rel * E + e];   // layer-1 dest / layer-2 src
    int c = cols[rel * E + e];   // layer-1 src / layer-2 dest
    unsigned old = atomicAdd(&hist[r >> 1], 1u << (16 * (r & 1)));
    rank16[rel * E + e] = (unsigned short)((old >> (16 * (r & 1))) & 0xFFFFu);
    if ((bm[c >> 5] >> (c & 31)) & 1u) {
      atomicAdd(&deg2[rel * N + c], 1);
      atomicOr(&flag_bm[r >> 5], 1u << (r & 31));   // h1[r] will be needed
      int p = atomicAdd(&s_cnt, 1);                 // LDS atomic, on-CU
      hsrc[rbase + p] = r;
      hpack[rbase + p] = (rel << 20) | c;           // N < 2^20
    }
  }
  __syncthreads();
  if (tid == 0) hcnt[rel * HIST_C + cidx] = s_cnt;
  unsigned* dst = &histw[(size_t)(rel * HIST_C + cidx) * WN];
  for (int i = tid; i < WN; i += HIST_THREADS) dst[i] = hist[i];
}

// ---------------- reduce copies -> in-place absolute bases + inv-weights ----------------
__global__ __launch_bounds__(256) void k_reduce(unsigned* __restrict__ histw,
                                                const float* __restrict__ a_soft,
                                                float* __restrict__ inv1,
                                                int* __restrict__ rowdeg, int N) {
  int WN = (N + 1) >> 1;
  int t = blockIdx.x * 256 + threadIdx.x;
  if (t >= WN) return;
  int d0 = 2 * t, d1 = 2 * t + 1;
  int tot0 = 0, tot1 = 0;
#pragma unroll
  for (int rel = 0; rel < 3; ++rel) {
    int run0 = tot0, run1 = tot1;
    for (int c = 0; c < HIST_C; ++c) {
      size_t idx = (size_t)(rel * HIST_C + c) * WN + t;
      unsigned w = histw[idx];
      histw[idx] = (unsigned)(run0 & 0xFFFF) | ((unsigned)(run1 & 0xFFFF) << 16);
      run0 += (int)(w & 0xFFFFu);
      run1 += (int)(w >> 16);
    }
    int dg0 = run0 - tot0, dg1 = run1 - tot1;
    float a = a_soft[rel];
    inv1[rel * N + d0] = a / (float)max(dg0, 1);
    if (d1 < N) inv1[rel * N + d1] = a / (float)max(dg1, 1);
    tot0 = run0; tot1 = run1;
  }
  rowdeg[d0] = tot0;
  if (d1 < N) rowdeg[d1] = tot1;
}

// ---------------- prefix sum over rowdeg ----------------

__global__ __launch_bounds__(256) void k_scan1(const int* __restrict__ rowdeg,
                                               int* __restrict__ row_ptr,
                                               int* __restrict__ chunk_sums, int N) {
  __shared__ int sd[256];
  int tid = threadIdx.x;
  int n0 = blockIdx.x * 1024 + tid * 4;
  int v[4];
#pragma unroll
  for (int i = 0; i < 4; ++i) {
    int n = n0 + i;
    v[i] = (n < N) ? rowdeg[n] : 0;
  }
  sd[tid] = v[0] + v[1] + v[2] + v[3];
  __syncthreads();
  for (int off = 1; off < 256; off <<= 1) {
    int t = (tid >= off) ? sd[tid - off] : 0;
    __syncthreads();
    sd[tid] += t;
    __syncthreads();
  }
  int run = tid ? sd[tid - 1] : 0;
#pragma unroll
  for (int i = 0; i < 4; ++i) {
    int n = n0 + i;
    if (n < N) row_ptr[n] = run;
    run += v[i];
  }
  if (tid == 255) chunk_sums[blockIdx.x] = sd[255];
}

__global__ __launch_bounds__(64) void k_scan2(const int* __restrict__ chunk_sums,
                                              int* __restrict__ chunk_offs,
                                              int nchunks, int* __restrict__ row_ptr, int N) {
  int lane = threadIdx.x;
  int mine = (lane < nchunks) ? chunk_sums[lane] : 0;
  int v = mine;
  for (int off = 1; off < 64; off <<= 1) {
    int t = __shfl_up(v, off, 64);
    if (lane >= off) v += t;
  }
  if (lane < nchunks) chunk_offs[lane] = v - mine;
  int total = __shfl(v, nchunks - 1, 64);
  if (lane == 0) row_ptr[N] = total;
}

__global__ __launch_bounds__(256) void k_scan3(int* __restrict__ row_ptr,
                                               const int* __restrict__ chunk_offs, int N) {
  int n = blockIdx.x * 256 + threadIdx.x;
  if (n < N) row_ptr[n] += chunk_offs[n >> 10];
}

// ---------------- atomic-free scatter (only for flagged dests) ----------------

__global__ __launch_bounds__(256) void k_scatter(const int* __restrict__ rows,
                                                 const int* __restrict__ cols,
                                                 const int* __restrict__ row_ptr,
                                                 const unsigned* __restrict__ histw,
                                                 const unsigned short* __restrict__ rank16,
                                                 const unsigned* __restrict__ flag_bm,
                                                 unsigned* __restrict__ esrc,
                                                 int N, int E, int chunk) {
  int e = blockIdx.x * 256 + threadIdx.x;
  int rel = blockIdx.y;
  if (e >= E) return;
  int d = rows[rel * E + e];
  if (!((flag_bm[d >> 5] >> (d & 31)) & 1u)) return;   // h1[d] never consumed
  int s = cols[rel * E + e];
  int WN = (N + 1) >> 1;
  int c = e / chunk;
  const unsigned short* cb = (const unsigned short*)histw;
  int pos = row_ptr[d] + (int)cb[(size_t)(rel * HIST_C + c) * (2 * WN) + d]
          + (int)rank16[rel * E + e];
  esrc[pos] = ((unsigned)rel << 16) | (unsigned)s;   // src < 2^16
}

// ---------------- GEMM1 via MFMA (hi/lo bf16 split, f32-grade accuracy) ----------------

__global__ __launch_bounds__(256) void k_gemm1(const float* __restrict__ A,
                                               const unsigned short* __restrict__ WThi,
                                               const unsigned short* __restrict__ WTlo,
                                               const float* __restrict__ bias,
                                               unsigned short* __restrict__ outbf,
                                               int M, int K) {
  __shared__ unsigned short sAhi[64 * 64], sAlo[64 * 64];     // 8 KB each
  __shared__ unsigned short sWhi[128 * 64], sWlo[128 * 64];   // 16 KB each
  char* pAhi = (char*)sAhi; char* pAlo = (char*)sAlo;
  char* pWhi = (char*)sWhi; char* pWlo = (char*)sWlo;
  int tid = threadIdx.x;
  int wave = tid >> 6, lane = tid & 63;
  int row0 = blockIdx.x * 64;
  f32x4 acc[8];
#pragma unroll
  for (int i = 0; i < 8; ++i) acc[i] = (f32x4){0.f, 0.f, 0.f, 0.f};

  for (int c = 0; c < 5; ++c) {
    int k0 = c * 64;
    __syncthreads();
    for (int i = tid; i < 1024; i += 256) {
      int r = i >> 4, q = i & 15;
      int gr = row0 + r, gk = k0 + q * 4;
      float4 v = make_float4(0.f, 0.f, 0.f, 0.f);
      if (gr < M && gk < K) v = *(const float4*)&A[(size_t)gr * K + gk];
      unsigned hh[2], ll[2];
      const float* vp = &v.x;
#pragma unroll
      for (int j = 0; j < 2; ++j) {
        unsigned short h0 = f2bf(vp[2 * j]),     h1 = f2bf(vp[2 * j + 1]);
        unsigned short l0 = f2bf(vp[2 * j] - bf2f(h0));
        unsigned short l1 = f2bf(vp[2 * j + 1] - bf2f(h1));
        hh[j] = (unsigned)h0 | ((unsigned)h1 << 16);
        ll[j] = (unsigned)l0 | ((unsigned)l1 << 16);
      }
      int byte = (r * 128 + q * 8) ^ ((r & 7) << 4);
      *(uint2*)(pAhi + byte) = make_uint2(hh[0], hh[1]);
      *(uint2*)(pAlo + byte) = make_uint2(ll[0], ll[1]);
    }
    for (int i = tid; i < 1024; i += 256) {
      int n = i >> 3, u = i & 7;
      size_t g = (size_t)n * KP + k0 + u * 8;
      int byte = (n * 128 + u * 16) ^ ((n & 7) << 4);
      *(uint4*)(pWhi + byte) = *(const uint4*)&WThi[g];
      *(uint4*)(pWlo + byte) = *(const uint4*)&WTlo[g];
    }
    __syncthreads();
#pragma unroll
    for (int ks = 0; ks < 2; ++ks) {
      int m = wave * 16 + (lane & 15);
      int kb = ks * 32 + (lane >> 4) * 8;
      bf16x8 ahi = *(const bf16x8*)(pAhi + ((m * 128 + kb * 2) ^ ((m & 7) << 4)));
      bf16x8 alo = *(const bf16x8*)(pAlo + ((m * 128 + kb * 2) ^ ((m & 7) << 4)));
#pragma unroll
      for (int nt = 0; nt < 8; ++nt) {
        int n = nt * 16 + (lane & 15);
        int wb = (n * 128 + kb * 2) ^ ((n & 7) << 4);
        bf16x8 bhi = *(const bf16x8*)(pWhi + wb);
        bf16x8 blo = *(const bf16x8*)(pWlo + wb);
        acc[nt] = __builtin_amdgcn_mfma_f32_16x16x32_bf16(ahi, bhi, acc[nt], 0, 0, 0);
        acc[nt] = __builtin_amdgcn_mfma_f32_16x16x32_bf16(ahi, blo, acc[nt], 0, 0, 0);
        acc[nt] = __builtin_amdgcn_mfma_f32_16x16x32_bf16(alo, bhi, acc[nt], 0, 0, 0);
      }
    }
  }
#pragma unroll
  for (int nt = 0; nt < 8; ++nt) {
    int n = nt * 16 + (lane & 15);
    float bv = bias[n];
#pragma unroll
    for (int j = 0; j < 4; ++j) {
      int m = row0 + wave * 16 + (lane >> 4) * 4 + j;
      if (m < M) outbf[(size_t)m * 128 + n] = f2bf(acc[nt][j] + bv);
    }
  }
}

// ---------------- layer-1 aggregation + LeakyReLU + L2 norm (flagged rows only) ----
// one wave per dest row; FOUR 16-lane groups each handle one edge per iteration,
// each lane reads 16B (8 bf16 cols) -> 4x memory-level parallelism vs 4B/lane.

__global__ __launch_bounds__(256) void k_agg_norm(const unsigned short* __restrict__ supp,
                                                  const int* __restrict__ row_ptr,
                                                  const unsigned* __restrict__ esrc,
                                                  const float* __restrict__ inv1,
                                                  const unsigned* __restrict__ flag_bm,
                                                  float* __restrict__ out, int N) {
  int wv = blockIdx.x * 4 + (threadIdx.x >> 6);
  if (wv >= N) return;
  int row = __builtin_amdgcn_readfirstlane(wv);
  if (!((flag_bm[row >> 5] >> (row & 31)) & 1u)) return;   // never consumed
  int lane = threadIdx.x & 63;
  int grp = lane >> 4;        // edge sub-slot 0..3
  int l16 = lane & 15;        // column block: cols l16*8 .. +7
  int s = row_ptr[row], e = row_ptr[row + 1];
  float w0 = inv1[row], w1 = inv1[N + row], w2 = inv1[2 * N + row];
  float acc[8] = {};
  for (int j = s; j < e; j += 4) {
    int jj = j + grp;
    bool act = jj < e;
    unsigned u = esrc[act ? jj : (e - 1)];
    int rel = (int)(u >> 16);
    int src = (int)(u & 0xFFFFu);
    float w = (rel == 0) ? w0 : ((rel == 1) ? w1 : w2);
    if (!act) w = 0.f;
    uint4 pv = *(const uint4*)&supp[(size_t)src * 128 + l16 * 8];
#pragma unroll
    for (int q = 0; q < 4; ++q) {
      unsigned p = (&pv.x)[q];
      acc[2 * q]     += w * __uint_as_float(p << 16);
      acc[2 * q + 1] += w * __uint_as_float(p & 0xFFFF0000u);
    }
  }
  // fold the 4 edge-groups (lane bits 4,5)
#pragma unroll
  for (int i = 0; i < 8; ++i) {
    acc[i] += __shfl_xor(acc[i], 16, 64);
    acc[i] += __shfl_xor(acc[i], 32, 64);
  }
  float ss = 0.f;
#pragma unroll
  for (int i = 0; i < 8; ++i) {
    acc[i] = acc[i] > 0.f ? acc[i] : LEAKY_SLOPE * acc[i];
    ss += acc[i] * acc[i];
  }
#pragma unroll
  for (int m = 1; m < 16; m <<= 1) ss += __shfl_xor(ss, m, 64);
  float inv = 1.0f / fmaxf(sqrtf(ss), 1e-12f);
  if (lane < 16) {
    *(float4*)&out[(size_t)row * 128 + l16 * 8] =
        make_float4(acc[0] * inv, acc[1] * inv, acc[2] * inv, acc[3] * inv);
    *(float4*)&out[(size_t)row * 128 + l16 * 8 + 4] =
        make_float4(acc[4] * inv, acc[5] * inv, acc[6] * inv, acc[7] * inv);
  }
}

// ---------------- layer-2 small path ----------------
__global__ __launch_bounds__(1024) void k_cnt2(const int* __restrict__ lidx,
                                               const int* __restrict__ lab_of,
                                               const int* __restrict__ deg2,
                                               const float* __restrict__ a_soft,
                                               int* __restrict__ hb_ptr,
                                               int* __restrict__ cnt2,
                                               int* __restrict__ fill2,
                                               float* __restrict__ sumw, int N, int L) {
  __shared__ int sd[1024];
  int t = threadIdx.x;
  int cnt = 0;
  if (t < L) {
    int d = lidx[t];
    int c0 = deg2[d], c1 = deg2[N + d], c2 = deg2[2 * N + d];
    if (lab_of[d] == t) cnt = c0 + c1 + c2;       // canonical slot owns the edges
    sumw[t] = a_soft[3] * (c0 > 0 ? 1.f : 0.f) +
              a_soft[4] * (c1 > 0 ? 1.f : 0.f) +
              a_soft[5] * (c2 > 0 ? 1.f : 0.f);
  }
  sd[t] = cnt;
  __syncthreads();
  for (int off = 1; off < 1024; off <<= 1) {
    int v = (t >= off) ? sd[t - off] : 0;
    __syncthreads();
    sd[t] += v;
    __syncthreads();
  }
  if (t < L) {
    int base = sd[t] - cnt;
    hb_ptr[t] = base;
    fill2[t] = base;
    cnt2[t] = cnt;
  }
}

// walk the 3*HIST_C private hit regions -> per-label CSR
__global__ __launch_bounds__(256) void k_scatter2(const int* __restrict__ hsrc,
                                                  const int* __restrict__ hpack,
                                                  const int* __restrict__ hcnt,
                                                  const int* __restrict__ lab_of,
                                                  int* __restrict__ fill2,
                                                  unsigned* __restrict__ hdata, int chunk) {
  int reg = blockIdx.x;
  int cnt = hcnt[reg];
  int rbase = reg * chunk;
  for (int i = threadIdx.x; i < cnt; i += 256) {
    int src = hsrc[rbase + i], pk = hpack[rbase + i];
    int rel = pk >> 20, d = pk & 0xFFFFF;
    int li = lab_of[d];
    int pos = atomicAdd(&fill2[li], 1);
    hdata[pos] = ((unsigned)rel << 16) | (unsigned)src;
  }
}

// aggregate h1 rows per canonical label slot (same 4-edge-group structure, f32 rows)
__global__ __launch_bounds__(256) void k_agg2(const float* __restrict__ h1,
                                              const int* __restrict__ hb_ptr,
                                              const int* __restrict__ cnt2,
                                              const unsigned* __restrict__ hdata,
                                              const int* __restrict__ lidx,
                                              const int* __restrict__ deg2,
                                              const float* __restrict__ a_soft,
                                              float* __restrict__ aggh, int N, int L) {
  int wv = blockIdx.x * 4 + (threadIdx.x >> 6);
  if (wv >= L) return;
  int li = __builtin_amdgcn_readfirstlane(wv);
  int lane = threadIdx.x & 63;
  int grp = lane >> 4, l16 = lane & 15;
  int d = lidx[li];
  int s = hb_ptr[li], e = s + cnt2[li];
  float w0 = a_soft[3] / (float)max(deg2[d], 1);
  float w1 = a_soft[4] / (float)max(deg2[N + d], 1);
  float w2 = a_soft[5] / (float)max(deg2[2 * N + d], 1);
  float acc[8] = {};
  for (int j = s; j < e; j += 4) {
    int jj = j + grp;
    bool act = jj < e;
    unsigned u = hdata[act ? jj : (e - 1)];
    int rel = (int)(u >> 16);
    int src = (int)(u & 0xFFFFu);
    float w = (rel == 0) ? w0 : ((rel == 1) ? w1 : w2);
    if (!act) w = 0.f;
    float4 v0 = *(const float4*)&h1[(size_t)src * 128 + l16 * 8];
    float4 v1 = *(const float4*)&h1[(size_t)src * 128 + l16 * 8 + 4];
    acc[0] += w * v0.x; acc[1] += w * v0.y; acc[2] += w * v0.z; acc[3] += w * v0.w;
    acc[4] += w * v1.x; acc[5] += w * v1.y; acc[6] += w * v1.z; acc[7] += w * v1.w;
  }
#pragma unroll
  for (int i = 0; i < 8; ++i) {
    acc[i] += __shfl_xor(acc[i], 16, 64);
    acc[i] += __shfl_xor(acc[i], 32, 64);
  }
  if (lane < 16) {
    *(float4*)&aggh[(size_t)li * 128 + l16 * 8] =
        make_float4(acc[0], acc[1], acc[2], acc[3]);
    *(float4*)&aggh[(size_t)li * 128 + l16 * 8 + 4] =
        make_float4(acc[4], acc[5], acc[6], acc[7]);
  }
}

// final: out[li] = normalize(leaky(aggh[canon(li)] @ W2 + b2*sumw[li]))
__global__ __launch_bounds__(256) void k_final(const float* __restrict__ aggh,
                                               const float* __restrict__ W2,
                                               const float* __restrict__ b2,
                                               const float* __restrict__ sumw,
                                               const int* __restrict__ lidx,
                                               const int* __restrict__ lab_of,
                                               float* __restrict__ out, int L) {
  __shared__ float sW[64][128];   // 32 KB
  __shared__ float sA[32][64];    // 8 KB
  __shared__ int s_c[32];
  __shared__ float s_sw[32];
  int tid = threadIdx.x;
  int wave = tid >> 6, lane = tid & 63;
  int lane2 = lane * 2;
  int row0 = blockIdx.x * 32;
  if (tid < 32) {
    int gr = row0 + tid;
    int c = 0; float sw = 0.f;
    if (gr < L) { c = lab_of[lidx[gr]]; sw = sumw[gr]; }
    s_c[tid] = c; s_sw[tid] = sw;
  }
  __syncthreads();
  float acc[8][2] = {};
  for (int k0 = 0; k0 < 128; k0 += 64) {
    __syncthreads();
    for (int i = tid; i < 64 * 32; i += 256) {
      int kk = i >> 5, c4 = i & 31;
      ((float4*)&sW[kk][0])[c4] = ((const float4*)&W2[(size_t)(k0 + kk) * 128])[c4];
    }
    for (int i = tid; i < 32 * 16; i += 256) {
      int r = i >> 4, kq = i & 15;
      int gr = row0 + r;
      float4 v = make_float4(0.f, 0.f, 0.f, 0.f);
      if (gr < L) v = ((const float4*)&aggh[(size_t)s_c[r] * 128 + k0])[kq];
      ((float4*)&sA[r][0])[kq] = v;
    }
    __syncthreads();
    const float* ap = &sA[wave * 8][0];
    for (int kk = 0; kk < 64; kk += 2) {
      float2 w0 = *(const float2*)&sW[kk][lane2];
      float2 w1 = *(const float2*)&sW[kk + 1][lane2];
#pragma unroll
      for (int r = 0; r < 8; ++r) {
        float2 av = *(const float2*)&ap[r * 64 + kk];
        acc[r][0] += av.x * w0.x + av.y * w1.x;
        acc[r][1] += av.x * w0.y + av.y * w1.y;
      }
    }
  }
  float2 bv = *(const float2*)&b2[lane2];
#pragma unroll
  for (int r = 0; r < 8; ++r) {
    int gr = row0 + wave * 8 + r;
    float sw = s_sw[wave * 8 + r];
    float ax = acc[r][0] + bv.x * sw;
    float ay = acc[r][1] + bv.y * sw;
    ax = ax > 0.f ? ax : LEAKY_SLOPE * ax;
    ay = ay > 0.f ? ay : LEAKY_SLOPE * ay;
    float ss = ax * ax + ay * ay;
#pragma unroll
    for (int m = 1; m < 64; m <<= 1) ss += __shfl_xor(ss, m, 64);
    float inv = 1.0f / fmaxf(sqrtf(ss), 1e-12f);
    if (gr < L) {
      *(float2*)&out[(size_t)gr * 128 + lane2] = make_float2(ax * inv, ay * inv);
    }
  }
}

// ---------------- host ----------------

extern "C" void kernel_launch(void* const* d_in, const int* in_sizes, int n_in,
                              void* d_out, int out_size, void* d_ws, size_t ws_size,
                              hipStream_t stream) {
  const float* feat  = (const float*)d_in[0];
  const float* w1    = (const float*)d_in[1];
  const float* b1    = (const float*)d_in[2];
  const float* w2    = (const float*)d_in[3];
  const float* b2    = (const float*)d_in[4];
  const float* a_att = (const float*)d_in[5];
  const float* r_att = (const float*)d_in[6];
  const int* rows    = (const int*)d_in[7];
  const int* cols    = (const int*)d_in[8];
  const int* lidx    = (const int*)d_in[9];

  const int F = 128;
  int K1 = in_sizes[1] / F;        // 300
  int N  = in_sizes[0] / K1;       // 50000
  int E  = in_sizes[7] / 3;        // 800000
  int L  = in_sizes[9];            // 1000
  float* outp = (float*)d_out;
  (void)n_in; (void)out_size; (void)ws_size;

  int WN = (N + 1) >> 1;
  int chunk = (E + HIST_C - 1) / HIST_C;

  char* base = (char*)d_ws;
  size_t off = 0;
  auto take = [&](size_t bytes) -> void* {
    size_t cur = (off + 255) & ~(size_t)255;
    off = cur + bytes;
    return (void*)(base + cur);
  };
  unsigned short* suppbf = (unsigned short*)take((size_t)N * F * 2);
  float* h1    = (float*)take((size_t)N * F * 4);
  unsigned* esrc = (unsigned*)take((size_t)3 * E * 4);     // reused as hdata later
  unsigned short* rank16 = (unsigned short*)take((size_t)3 * E * 2);
  unsigned* histw = (unsigned*)take((size_t)3 * HIST_C * WN * 4);
  float* inv1  = (float*)take((size_t)3 * N * 4);
  int* rowdeg  = (int*)take((size_t)N * 4);
  int* row_ptr = (int*)take((size_t)(N + 1) * 4);
  int* hsrc  = (int*)take((size_t)3 * HIST_C * chunk * 4);
  int* hpack = (int*)take((size_t)3 * HIST_C * chunk * 4);
  unsigned short* WThi = (unsigned short*)take((size_t)128 * KP * 2);
  unsigned short* WTlo = (unsigned short*)take((size_t)128 * KP * 2);
  float* aggh = (float*)take((size_t)1024 * F * 4);
  int* lab_of = (int*)take((size_t)N * 4);
  int nb = (N + 31) / 32;
  int zn = 3 * N + 2 * nb;                      // deg2 + bm + flag_bm
  int* deg2 = (int*)take((size_t)zn * 4);
  unsigned* bm = (unsigned*)(deg2 + 3 * N);
  unsigned* flag_bm = bm + nb;
  int* hcnt = (int*)take((size_t)(3 * HIST_C + 1) * 4);
  int* hb_ptr = (int*)take(1024 * 4);
  int* cnt2   = (int*)take(1024 * 4);
  int* fill2  = (int*)take(1024 * 4);
  float* sumw = (float*)take(1024 * 4);
  float* a_soft = (float*)take(64);
  int* chunk_sums = (int*)take(256);
  int* chunk_offs = (int*)take(256);
  unsigned* hdata = esrc;   // esrc is dead after k_agg_norm

  int nchunks = (N + 1023) / 1024;
  size_t shbytes = (size_t)WN * 4;
  hipFuncSetAttribute((const void*)k_hist, hipFuncAttributeMaxDynamicSharedMemorySize,
                      (int)shbytes);

  hipLaunchKernelGGL(k_zero, dim3((zn + 255) / 256), dim3(256), 0, stream, deg2, zn, 0);
  hipLaunchKernelGGL(k_zero, dim3((N + 255) / 256), dim3(256), 0, stream, lab_of, N, -1);
  hipLaunchKernelGGL(k_softmax3, dim3(1), dim3(64), 0, stream, a_att, r_att, a_soft);
  hipLaunchKernelGGL(k_lab, dim3((L + 255) / 256), dim3(256), 0, stream, lidx, bm, lab_of, L);
  hipLaunchKernelGGL(k_prep, dim3((128 * KP + 255) / 256), dim3(256), 0, stream,
                     w1, WThi, WTlo, K1);
  hipLaunchKernelGGL(k_hist, dim3(HIST_C, 3), dim3(HIST_THREADS), shbytes, stream,
                     rows, cols, bm, deg2, flag_bm, hcnt, hsrc, hpack, rank16, histw,
                     N, E, chunk);
  hipLaunchKernelGGL(k_gemm1, dim3((N + 63) / 64), dim3(256), 0, stream,
                     feat, WThi, WTlo, b1, suppbf, N, K1);
  hipLaunchKernelGGL(k_reduce, dim3((WN + 255) / 256), dim3(256), 0, stream,
                     histw, a_soft, inv1, rowdeg, N);
  hipLaunchKernelGGL(k_scan1, dim3(nchunks), dim3(256), 0, stream, rowdeg, row_ptr, chunk_sums, N);
  hipLaunchKernelGGL(k_scan2, dim3(1), dim3(64), 0, stream, chunk_sums, chunk_offs, nchunks, row_ptr, N);
  hipLaunchKernelGGL(k_scan3, dim3((N + 255) / 256), dim3(256), 0, stream, row_ptr, chunk_offs, N);
  hipLaunchKernelGGL(k_scatter, dim3((E + 255) / 256, 3), dim3(256), 0, stream,
                     rows, cols, row_ptr, histw, rank16, flag_bm, esrc, N, E, chunk);
  hipLaunchKernelGGL(k_agg_norm, dim3((N + 3) / 4), dim3(256), 0, stream,
                     suppbf, row_ptr, esrc, inv1, flag_bm, h1, N);
  hipLaunchKernelGGL(k_cnt2, dim3(1), dim3(1024), 0, stream,
                     lidx, lab_of, deg2, a_soft, hb_ptr, cnt2, fill2, sumw, N, L);
  hipLaunchKernelGGL(k_scatter2, dim3(3 * HIST_C), dim3(256), 0, stream,
                     hsrc, hpack, hcnt, lab_of, fill2, hdata, chunk);
  hipLaunchKernelGGL(k_agg2, dim3((L + 3) / 4), dim3(256), 0, stream,
                     h1, hb_ptr, cnt2, hdata, lidx, deg2, a_soft, aggh, N, L);
  hipLaunchKernelGGL(k_final, dim3((L + 31) / 32), dim3(256), 0, stream,
                     aggh, w2, b2, sumw, lidx, lab_of, outp, L);
}